// Round 1
// baseline (1402.847 us; speedup 1.0000x reference)
//
#include <hip/hip_runtime.h>
#include <stdint.h>

typedef __bf16 bf16;
typedef __bf16 bf16x4 __attribute__((ext_vector_type(4)));
typedef __bf16 bf16x8 __attribute__((ext_vector_type(8)));
typedef float f32x4 __attribute__((ext_vector_type(4)));

#define SEQ 2048
#define DIM 1024
#define NHEAD 16
#define HDIM 64
#define HID 2816
#define NLAYER 4

__device__ __forceinline__ void gload_lds16(const void* g, void* l) {
  __builtin_amdgcn_global_load_lds(
      (const __attribute__((address_space(1))) void*)g,
      (__attribute__((address_space(3))) void*)l, 16, 0, 0);
}

// ---------------- GEMM: C[M,N] = A[M,K] @ B[N,K]^T ----------------
// MODE 0: Cb[idx] = (bf16)acc.  MODE 1: Cf[idx] = R[idx] + acc (f32 residual).
template <int MODE>
__global__ __launch_bounds__(256) void gemm_bt(
    const bf16* __restrict__ A, const bf16* __restrict__ B,
    bf16* __restrict__ Cb, float* __restrict__ Cf, const float* R,
    int M, int N, int K)
{
  __shared__ bf16 As[128 * 32];
  __shared__ bf16 Bs[128 * 32];
  const int tid  = threadIdx.x;
  const int wv   = tid >> 6;
  const int lane = tid & 63;
  const int lo = lane & 15, hi = lane >> 4;
  const int row0 = blockIdx.y * 128;
  const int col0 = blockIdx.x * 128;
  const int wr = (wv >> 1) * 64;
  const int wc = (wv & 1) * 64;

  f32x4 acc[4][4];
  const f32x4 zero = {0.f, 0.f, 0.f, 0.f};
#pragma unroll
  for (int m = 0; m < 4; ++m)
#pragma unroll
    for (int n = 0; n < 4; ++n) acc[m][n] = zero;

  const bf16* ag = A + (size_t)(row0 + (tid >> 2)) * K + (tid & 3) * 8;
  const bf16* bg = B + (size_t)(col0 + (tid >> 2)) * K + (tid & 3) * 8;
  bf16* as0 = As + wv * 512;
  bf16* bs0 = Bs + wv * 512;

  for (int k0 = 0; k0 < K; k0 += 32) {
    gload_lds16(ag,                 as0);
    gload_lds16(ag + (size_t)64*K,  as0 + 2048);
    gload_lds16(bg,                 bs0);
    gload_lds16(bg + (size_t)64*K,  bs0 + 2048);
    ag += 32; bg += 32;
    __syncthreads();
    bf16x8 af[4], bfv[4];
#pragma unroll
    for (int m = 0; m < 4; ++m)
      af[m] = *(const bf16x8*)&As[(wr + m * 16 + lo) * 32 + hi * 8];
#pragma unroll
    for (int n = 0; n < 4; ++n)
      bfv[n] = *(const bf16x8*)&Bs[(wc + n * 16 + lo) * 32 + hi * 8];
#pragma unroll
    for (int m = 0; m < 4; ++m)
#pragma unroll
      for (int n = 0; n < 4; ++n)
        acc[m][n] = __builtin_amdgcn_mfma_f32_16x16x32_bf16(af[m], bfv[n], acc[m][n], 0, 0, 0);
    __syncthreads();
  }

#pragma unroll
  for (int m = 0; m < 4; ++m)
#pragma unroll
    for (int n = 0; n < 4; ++n)
#pragma unroll
      for (int r = 0; r < 4; ++r) {
        const int row = row0 + wr + m * 16 + hi * 4 + r;
        const int col = col0 + wc + n * 16 + lo;
        const size_t idx = (size_t)row * N + col;
        if (MODE == 0) Cb[idx] = (bf16)acc[m][n][r];
        else           Cf[idx] = R[idx] + acc[m][n][r];
      }
}

// ---------------- flash attention: 1 wave per (head, 32 q rows) ----------------
__global__ __launch_bounds__(64) void attn_kernel(const bf16* __restrict__ qkv,
    const bf16* __restrict__ vt, bf16* __restrict__ outb)
{
  __shared__ bf16 plds[32 * 32];
  const int lane = threadIdx.x;
  const int lo = lane & 15, hi = lane >> 4;
  const int q0 = blockIdx.x * 32;
  const int hh = blockIdx.y;

  bf16x8 qf[2][2];
#pragma unroll
  for (int m = 0; m < 2; ++m)
#pragma unroll
    for (int kd = 0; kd < 2; ++kd)
      qf[m][kd] = *(const bf16x8*)&qkv[(size_t)(q0 + m*16 + lo)*3072 + hh*64 + kd*32 + hi*8];

  const f32x4 zero = {0.f,0.f,0.f,0.f};
  f32x4 o[2][4];
  float mrun[2][4], lrun[2][4];
#pragma unroll
  for (int m = 0; m < 2; ++m) {
#pragma unroll
    for (int nd = 0; nd < 4; ++nd) o[m][nd] = zero;
#pragma unroll
    for (int r = 0; r < 4; ++r) { mrun[m][r] = -1e30f; lrun[m][r] = 0.f; }
  }

  const bf16* kbase = qkv + 1024 + hh*64;
  const bf16* vbase = vt + (size_t)hh*64*2048;

  for (int j0 = 0; j0 < SEQ; j0 += 32) {
    bf16x8 kf[2][2];
#pragma unroll
    for (int n = 0; n < 2; ++n)
#pragma unroll
      for (int kd = 0; kd < 2; ++kd)
        kf[n][kd] = *(const bf16x8*)&kbase[(size_t)(j0 + n*16 + lo)*3072 + kd*32 + hi*8];
    f32x4 sa[2][2];
#pragma unroll
    for (int m = 0; m < 2; ++m)
#pragma unroll
      for (int n = 0; n < 2; ++n) {
        sa[m][n] = zero;
#pragma unroll
        for (int kd = 0; kd < 2; ++kd)
          sa[m][n] = __builtin_amdgcn_mfma_f32_16x16x32_bf16(qf[m][kd], kf[n][kd], sa[m][n], 0,0,0);
      }
    float pv[2][2][4];
#pragma unroll
    for (int m = 0; m < 2; ++m)
#pragma unroll
      for (int r = 0; r < 4; ++r) {
        float v0 = sa[m][0][r] * 0.125f;
        float v1 = sa[m][1][r] * 0.125f;
        float mx = fmaxf(v0, v1);
#pragma unroll
        for (int off = 1; off < 16; off <<= 1) mx = fmaxf(mx, __shfl_xor(mx, off));
        float mnew = fmaxf(mrun[m][r], mx);
        float corr = __expf(mrun[m][r] - mnew);
        float p0 = __expf(v0 - mnew);
        float p1 = __expf(v1 - mnew);
        float ps = p0 + p1;
#pragma unroll
        for (int off = 1; off < 16; off <<= 1) ps += __shfl_xor(ps, off);
        lrun[m][r] = lrun[m][r]*corr + ps;
        mrun[m][r] = mnew;
        pv[m][0][r] = p0; pv[m][1][r] = p1;
#pragma unroll
        for (int nd = 0; nd < 4; ++nd) o[m][nd][r] *= corr;
      }
#pragma unroll
    for (int m = 0; m < 2; ++m)
#pragma unroll
      for (int n = 0; n < 2; ++n)
#pragma unroll
        for (int r = 0; r < 4; ++r)
          plds[(m*16 + hi*4 + r)*32 + n*16 + lo] = (bf16)pv[m][n][r];
    __syncthreads();
    bf16x8 pa[2];
#pragma unroll
    for (int m = 0; m < 2; ++m)
      pa[m] = *(const bf16x8*)&plds[(m*16 + lo)*32 + hi*8];
    bf16x8 vb[4];
#pragma unroll
    for (int nd = 0; nd < 4; ++nd)
      vb[nd] = *(const bf16x8*)&vbase[(size_t)(nd*16 + lo)*2048 + j0 + hi*8];
#pragma unroll
    for (int m = 0; m < 2; ++m)
#pragma unroll
      for (int nd = 0; nd < 4; ++nd)
        o[m][nd] = __builtin_amdgcn_mfma_f32_16x16x32_bf16(pa[m], vb[nd], o[m][nd], 0,0,0);
    __syncthreads();
  }
#pragma unroll
  for (int m = 0; m < 2; ++m)
#pragma unroll
    for (int nd = 0; nd < 4; ++nd)
#pragma unroll
      for (int r = 0; r < 4; ++r) {
        int row = q0 + m*16 + hi*4 + r;
        int col = hh*64 + nd*16 + lo;
        outb[(size_t)row*DIM + col] = (bf16)(o[m][nd][r] / lrun[m][r]);
      }
}

// ---------------- small kernels ----------------
__global__ __launch_bounds__(256) void rope_init_kernel(float* __restrict__ ct, float* __restrict__ st) {
  int idx = blockIdx.x * 256 + threadIdx.x;
  if (idx >= SEQ * 32) return;
  int s = idx >> 5, i = idx & 31;
  float inv = powf(10000.0f, -(float)i / 32.0f);
  float f = (float)s * inv;
  ct[idx] = cosf(f);
  st[idx] = sinf(f);
}

__global__ __launch_bounds__(256) void cast_kernel(const float* __restrict__ src,
    bf16* __restrict__ dst, int perLayer, int dstStride, int dstOff, int L)
{
  int i = blockIdx.x * 256 + threadIdx.x;
  int e = i * 4;
  if (e >= perLayer * L) return;
  int l = e / perLayer;
  int o = e - l * perLayer;
  float4 v = *(const float4*)(src + e);
  bf16x4 b;
  b[0] = (bf16)v.x; b[1] = (bf16)v.y; b[2] = (bf16)v.z; b[3] = (bf16)v.w;
  *(bf16x4*)(dst + (size_t)l * dstStride + dstOff + o) = b;
}

__global__ __launch_bounds__(256) void embed_kernel(const int* __restrict__ tok,
    const float* __restrict__ emb, float* __restrict__ h)
{
  int s = blockIdx.x, t = threadIdx.x;
  int v = tok[s];
  ((float4*)(h + (size_t)s * DIM))[t] = ((const float4*)(emb + (size_t)v * DIM))[t];
}

__global__ __launch_bounds__(256) void rmsnorm_kernel(const float* __restrict__ h,
    const float* __restrict__ w, bf16* __restrict__ outb)
{
  int row = blockIdx.x, tid = threadIdx.x;
  float4 v = ((const float4*)(h + (size_t)row * DIM))[tid];
  float ss = v.x*v.x + v.y*v.y + v.z*v.z + v.w*v.w;
#pragma unroll
  for (int off = 1; off < 64; off <<= 1) ss += __shfl_xor(ss, off);
  __shared__ float red[4];
  if ((tid & 63) == 0) red[tid >> 6] = ss;
  __syncthreads();
  float tot = red[0] + red[1] + red[2] + red[3];
  float inv = rsqrtf(tot * (1.0f / DIM) + 1e-5f);
  float4 wv4 = ((const float4*)w)[tid];
  bf16x4 o;
  o[0] = (bf16)(v.x * inv * wv4.x);
  o[1] = (bf16)(v.y * inv * wv4.y);
  o[2] = (bf16)(v.z * inv * wv4.z);
  o[3] = (bf16)(v.w * inv * wv4.w);
  ((bf16x4*)(outb + (size_t)row * DIM))[tid] = o;
}

__global__ __launch_bounds__(256) void final_rms_kernel(const float* __restrict__ hrow,
    const float* __restrict__ w, float* __restrict__ fl)
{
  int tid = threadIdx.x;
  float4 v = ((const float4*)hrow)[tid];
  float ss = v.x*v.x + v.y*v.y + v.z*v.z + v.w*v.w;
#pragma unroll
  for (int off = 1; off < 64; off <<= 1) ss += __shfl_xor(ss, off);
  __shared__ float red[4];
  if ((tid & 63) == 0) red[tid >> 6] = ss;
  __syncthreads();
  float tot = red[0] + red[1] + red[2] + red[3];
  float inv = rsqrtf(tot * (1.0f / DIM) + 1e-5f);
  float4 wv4 = ((const float4*)w)[tid];
  float4 o;
  o.x = v.x * inv * wv4.x;
  o.y = v.y * inv * wv4.y;
  o.z = v.z * inv * wv4.z;
  o.w = v.w * inv * wv4.w;
  ((float4*)fl)[tid] = o;
}

__global__ __launch_bounds__(256) void rope_kernel(bf16* __restrict__ qkv,
    const float* __restrict__ ct, const float* __restrict__ st)
{
  int idx = blockIdx.x * 256 + threadIdx.x;
  if (idx >= SEQ * 512) return;
  int s = idx >> 9;
  int rem = idx & 511;
  int h = rem >> 5, i = rem & 31;
  float c = ct[s * 32 + i], sn = st[s * 32 + i];
  size_t base = (size_t)s * 3072 + h * 64 + 2 * i;
#pragma unroll
  for (int part = 0; part < 2; ++part) {
    bf16* p = qkv + base + part * 1024;
    float xr = (float)p[0], xi = (float)p[1];
    p[0] = (bf16)(xr * c - xi * sn);
    p[1] = (bf16)(xr * sn + xi * c);
  }
}

__global__ __launch_bounds__(256) void vtrans_kernel(const bf16* __restrict__ qkv,
    bf16* __restrict__ vt)
{
  int i = blockIdx.x * 256 + threadIdx.x;
  if (i >= SEQ * DIM) return;
  int d = i >> 11, j = i & 2047;
  vt[(size_t)d * SEQ + j] = qkv[(size_t)j * 3072 + 2048 + d];
}

__global__ __launch_bounds__(256) void silu_kernel(const bf16* __restrict__ ug,
    bf16* __restrict__ hb)
{
  int i = blockIdx.x * 256 + threadIdx.x;
  int s = i / 352, j8 = (i - s * 352) * 8;
  if (s >= SEQ) return;
  bf16x8 u = *(const bf16x8*)&ug[(size_t)s * 5632 + j8];
  bf16x8 g = *(const bf16x8*)&ug[(size_t)s * 5632 + 2816 + j8];
  bf16x8 o;
#pragma unroll
  for (int t = 0; t < 8; ++t) {
    float x = (float)u[t];
    float y = x / (1.f + __expf(-x)) * (float)g[t];
    o[t] = (bf16)y;
  }
  *(bf16x8*)&hb[(size_t)s * HID + j8] = o;
}

__global__ __launch_bounds__(64) void logits_kernel(const float* __restrict__ fl,
    const float* __restrict__ ow, float* __restrict__ outp)
{
  int v = blockIdx.x, lane = threadIdx.x;
  const float* row = ow + (size_t)v * DIM;
  float s = 0.f;
#pragma unroll
  for (int t = 0; t < 16; ++t) {
    int d = t * 64 + lane;
    s += fl[d] * row[d];
  }
#pragma unroll
  for (int off = 1; off < 64; off <<= 1) s += __shfl_xor(s, off);
  if (lane == 0) outp[v] = s;
}

// ---------------- host ----------------
extern "C" void kernel_launch(void* const* d_in, const int* in_sizes, int n_in,
                              void* d_out, int out_size, void* d_ws, size_t ws_size,
                              hipStream_t stream)
{
  const int*   tokens = (const int*)  d_in[0];
  const float* temb   = (const float*)d_in[1];
  const float* wq  = (const float*)d_in[2];
  const float* wk  = (const float*)d_in[3];
  const float* wvv = (const float*)d_in[4];
  const float* wo  = (const float*)d_in[5];
  const float* w1  = (const float*)d_in[6];
  const float* w2  = (const float*)d_in[7];
  const float* w3  = (const float*)d_in[8];
  const float* anw = (const float*)d_in[9];
  const float* fnw = (const float*)d_in[10];
  const float* finw= (const float*)d_in[11];
  const float* outw= (const float*)d_in[12];
  float* out = (float*)d_out;

  char* wsp = (char*)d_ws;
  size_t off = 0;
  auto take = [&](size_t bytes) -> void* {
    void* r = wsp + off;
    off += (bytes + 255) & ~(size_t)255;
    return r;
  };
  bf16* wqkv = (bf16*)take((size_t)NLAYER * 3072 * DIM * 2);
  bf16* wob  = (bf16*)take((size_t)NLAYER * DIM * DIM * 2);
  bf16* w13  = (bf16*)take((size_t)NLAYER * 2 * HID * DIM * 2);
  bf16* w2b  = (bf16*)take((size_t)NLAYER * DIM * HID * 2);
  float* h   = (float*)take((size_t)SEQ * DIM * 4);
  bf16* xn   = (bf16*)take((size_t)SEQ * DIM * 2);
  bf16* qkvb = (bf16*)take((size_t)SEQ * 3072 * 2);
  bf16* vtb  = (bf16*)take((size_t)DIM * SEQ * 2);
  bf16* attnb= (bf16*)take((size_t)SEQ * DIM * 2);
  bf16* ugb  = (bf16*)take((size_t)SEQ * 2 * HID * 2);
  bf16* hbb  = (bf16*)take((size_t)SEQ * HID * 2);
  float* ct  = (float*)take((size_t)SEQ * 32 * 4);
  float* st  = (float*)take((size_t)SEQ * 32 * 4);
  float* fl  = (float*)take((size_t)DIM * 4);

  rope_init_kernel<<<SEQ * 32 / 256, 256, 0, stream>>>(ct, st);

  const int PLd = DIM * DIM;        // 1048576
  const int PLh = HID * DIM;        // 2883584
  cast_kernel<<<PLd * NLAYER / 1024, 256, 0, stream>>>(wq,  wqkv, PLd, 3 * PLd, 0,       NLAYER);
  cast_kernel<<<PLd * NLAYER / 1024, 256, 0, stream>>>(wk,  wqkv, PLd, 3 * PLd, PLd,     NLAYER);
  cast_kernel<<<PLd * NLAYER / 1024, 256, 0, stream>>>(wvv, wqkv, PLd, 3 * PLd, 2 * PLd, NLAYER);
  cast_kernel<<<PLd * NLAYER / 1024, 256, 0, stream>>>(wo,  wob,  PLd, PLd,     0,       NLAYER);
  cast_kernel<<<PLh * NLAYER / 1024, 256, 0, stream>>>(w1,  w13,  PLh, 2 * PLh, 0,       NLAYER);
  cast_kernel<<<PLh * NLAYER / 1024, 256, 0, stream>>>(w3,  w13,  PLh, 2 * PLh, PLh,     NLAYER);
  cast_kernel<<<PLh * NLAYER / 1024, 256, 0, stream>>>(w2,  w2b,  PLh, PLh,     0,       NLAYER);

  embed_kernel<<<SEQ, 256, 0, stream>>>(tokens, temb, h);

  for (int l = 0; l < NLAYER; ++l) {
    const bf16* lwqkv = wqkv + (size_t)l * 3 * PLd;
    const bf16* lwo   = wob  + (size_t)l * PLd;
    const bf16* lw13  = w13  + (size_t)l * 2 * PLh;
    const bf16* lw2   = w2b  + (size_t)l * PLh;

    rmsnorm_kernel<<<SEQ, 256, 0, stream>>>(h, anw + l * DIM, xn);
    gemm_bt<0><<<dim3(24, 16), 256, 0, stream>>>(xn, lwqkv, qkvb, nullptr, nullptr, SEQ, 3072, DIM);
    rope_kernel<<<SEQ * 512 / 256, 256, 0, stream>>>(qkvb, ct, st);
    vtrans_kernel<<<SEQ * DIM / 256, 256, 0, stream>>>(qkvb, vtb);
    attn_kernel<<<dim3(64, 16), 64, 0, stream>>>(qkvb, vtb, attnb);
    gemm_bt<1><<<dim3(8, 16), 256, 0, stream>>>(attnb, lwo, nullptr, h, h, SEQ, DIM, DIM);
    rmsnorm_kernel<<<SEQ, 256, 0, stream>>>(h, fnw + l * DIM, xn);
    gemm_bt<0><<<dim3(44, 16), 256, 0, stream>>>(xn, lw13, ugb, nullptr, nullptr, SEQ, 2 * HID, DIM);
    silu_kernel<<<SEQ * HID / 8 / 256, 256, 0, stream>>>(ugb, hbb);
    gemm_bt<1><<<dim3(8, 16), 256, 0, stream>>>(hbb, lw2, nullptr, h, h, SEQ, DIM, HID);
  }

  final_rms_kernel<<<1, 256, 0, stream>>>(h + (size_t)(SEQ - 1) * DIM, finw, fl);
  logits_kernel<<<256, 64, 0, stream>>>(fl, outw, out);
}

// Round 2
// 1199.843 us; speedup vs baseline: 1.1692x; 1.1692x over previous
//
#include <hip/hip_runtime.h>
#include <stdint.h>

typedef __bf16 bf16;
typedef __bf16 bf16x4 __attribute__((ext_vector_type(4)));
typedef __bf16 bf16x8 __attribute__((ext_vector_type(8)));
typedef float f32x4 __attribute__((ext_vector_type(4)));

#define SEQ 2048
#define DIM 1024
#define NHEAD 16
#define HDIM 64
#define HID 2816
#define NLAYER 4

__device__ __forceinline__ void gload_lds16(const void* g, void* l) {
  __builtin_amdgcn_global_load_lds(
      (const __attribute__((address_space(1))) void*)g,
      (__attribute__((address_space(3))) void*)l, 16, 0, 0);
}

// ---------------- GEMM: C[M,N] = A[M,K] @ B[N,K]^T ----------------
// MODE 0: Cb[idx] = (bf16)acc.  MODE 1: Cf[idx] = R[idx] + acc (f32 residual).
template <int MODE>
__global__ __launch_bounds__(256) void gemm_bt(
    const bf16* __restrict__ A, const bf16* __restrict__ B,
    bf16* __restrict__ Cb, float* __restrict__ Cf, const float* R,
    int M, int N, int K)
{
  __shared__ bf16 As[128 * 32];
  __shared__ bf16 Bs[128 * 32];
  const int tid  = threadIdx.x;
  const int wv   = tid >> 6;
  const int lane = tid & 63;
  const int lo = lane & 15, hi = lane >> 4;
  const int row0 = blockIdx.y * 128;
  const int col0 = blockIdx.x * 128;
  const int wr = (wv >> 1) * 64;
  const int wc = (wv & 1) * 64;

  f32x4 acc[4][4];
  const f32x4 zero = {0.f, 0.f, 0.f, 0.f};
#pragma unroll
  for (int m = 0; m < 4; ++m)
#pragma unroll
    for (int n = 0; n < 4; ++n) acc[m][n] = zero;

  const bf16* ag = A + (size_t)(row0 + (tid >> 2)) * K + (tid & 3) * 8;
  const bf16* bg = B + (size_t)(col0 + (tid >> 2)) * K + (tid & 3) * 8;
  bf16* as0 = As + wv * 512;
  bf16* bs0 = Bs + wv * 512;

  for (int k0 = 0; k0 < K; k0 += 32) {
    gload_lds16(ag,                 as0);
    gload_lds16(ag + (size_t)64*K,  as0 + 2048);
    gload_lds16(bg,                 bs0);
    gload_lds16(bg + (size_t)64*K,  bs0 + 2048);
    ag += 32; bg += 32;
    __syncthreads();
    bf16x8 af[4], bfv[4];
#pragma unroll
    for (int m = 0; m < 4; ++m)
      af[m] = *(const bf16x8*)&As[(wr + m * 16 + lo) * 32 + hi * 8];
#pragma unroll
    for (int n = 0; n < 4; ++n)
      bfv[n] = *(const bf16x8*)&Bs[(wc + n * 16 + lo) * 32 + hi * 8];
#pragma unroll
    for (int m = 0; m < 4; ++m)
#pragma unroll
      for (int n = 0; n < 4; ++n)
        acc[m][n] = __builtin_amdgcn_mfma_f32_16x16x32_bf16(af[m], bfv[n], acc[m][n], 0, 0, 0);
    __syncthreads();
  }

#pragma unroll
  for (int m = 0; m < 4; ++m)
#pragma unroll
    for (int n = 0; n < 4; ++n)
#pragma unroll
      for (int r = 0; r < 4; ++r) {
        const int row = row0 + wr + m * 16 + hi * 4 + r;
        const int col = col0 + wc + n * 16 + lo;
        const size_t idx = (size_t)row * N + col;
        if (MODE == 0) Cb[idx] = (bf16)acc[m][n][r];
        else           Cf[idx] = R[idx] + acc[m][n][r];
      }
}

// ---------------- flash attention: 4-wave KV-split per (head, 32 q rows) ----------------
// Block: 256 threads. Wave w processes KV tiles j0 = (w + 4t)*32, t=0..15, with
// private online-softmax state; partials merged through LDS at the end.
__global__ __launch_bounds__(256) void attn_kernel(const bf16* __restrict__ qkv,
    const bf16* __restrict__ vt, bf16* __restrict__ outb)
{
  // Merge buffer: Osh[w*64+lane][33] floats (padded stride, conflict-free).
  // First 8 KB aliased as per-wave P-transpose slices during the main loop.
  __shared__ float Osh[4 * 64 * 33];
  __shared__ float msh[4][4][2][4];
  __shared__ float lsh[4][4][2][4];

  const int tid  = threadIdx.x;
  const int wv   = tid >> 6;
  const int lane = tid & 63;
  const int lo = lane & 15, hi = lane >> 4;
  const int hh = blockIdx.x;        // head fastest -> each head pinned to one XCD's L2
  const int q0 = blockIdx.y * 32;

  bf16* plds = (bf16*)Osh + wv * 1024;   // 2 KB per-wave slice (within first 8 KB)

  bf16x8 qf[2][2];
#pragma unroll
  for (int m = 0; m < 2; ++m)
#pragma unroll
    for (int kd = 0; kd < 2; ++kd)
      qf[m][kd] = *(const bf16x8*)&qkv[(size_t)(q0 + m*16 + lo)*3072 + hh*64 + kd*32 + hi*8];

  const f32x4 zero = {0.f,0.f,0.f,0.f};
  f32x4 o[2][4];
  float mrun[2][4], lrun[2][4];
#pragma unroll
  for (int m = 0; m < 2; ++m) {
#pragma unroll
    for (int nd = 0; nd < 4; ++nd) o[m][nd] = zero;
#pragma unroll
    for (int r = 0; r < 4; ++r) { mrun[m][r] = -1e30f; lrun[m][r] = 0.f; }
  }

  const bf16* kbase = qkv + 1024 + hh*64;
  const bf16* vbase = vt + (size_t)hh*64*2048;

  for (int t = 0; t < 16; ++t) {
    const int j0 = (wv + 4*t) * 32;
    bf16x8 kf[2][2];
#pragma unroll
    for (int n = 0; n < 2; ++n)
#pragma unroll
      for (int kd = 0; kd < 2; ++kd)
        kf[n][kd] = *(const bf16x8*)&kbase[(size_t)(j0 + n*16 + lo)*3072 + kd*32 + hi*8];
    f32x4 sa[2][2];
#pragma unroll
    for (int m = 0; m < 2; ++m)
#pragma unroll
      for (int n = 0; n < 2; ++n) {
        sa[m][n] = zero;
#pragma unroll
        for (int kd = 0; kd < 2; ++kd)
          sa[m][n] = __builtin_amdgcn_mfma_f32_16x16x32_bf16(qf[m][kd], kf[n][kd], sa[m][n], 0,0,0);
      }
    float pv[2][2][4];
#pragma unroll
    for (int m = 0; m < 2; ++m)
#pragma unroll
      for (int r = 0; r < 4; ++r) {
        float v0 = sa[m][0][r] * 0.125f;
        float v1 = sa[m][1][r] * 0.125f;
        float mx = fmaxf(v0, v1);
#pragma unroll
        for (int off = 1; off < 16; off <<= 1) mx = fmaxf(mx, __shfl_xor(mx, off));
        float mnew = fmaxf(mrun[m][r], mx);
        float corr = __expf(mrun[m][r] - mnew);
        float p0 = __expf(v0 - mnew);
        float p1 = __expf(v1 - mnew);
        float ps = p0 + p1;
#pragma unroll
        for (int off = 1; off < 16; off <<= 1) ps += __shfl_xor(ps, off);
        lrun[m][r] = lrun[m][r]*corr + ps;
        mrun[m][r] = mnew;
        pv[m][0][r] = p0; pv[m][1][r] = p1;
#pragma unroll
        for (int nd = 0; nd < 4; ++nd) o[m][nd][r] *= corr;
      }
    // per-wave P transpose through private LDS slice (same-wave DS ordering)
#pragma unroll
    for (int m = 0; m < 2; ++m)
#pragma unroll
      for (int n = 0; n < 2; ++n)
#pragma unroll
        for (int r = 0; r < 4; ++r)
          plds[(m*16 + hi*4 + r)*32 + n*16 + lo] = (bf16)pv[m][n][r];
    bf16x8 pa[2];
#pragma unroll
    for (int m = 0; m < 2; ++m)
      pa[m] = *(const bf16x8*)&plds[(m*16 + lo)*32 + hi*8];
    bf16x8 vb[4];
#pragma unroll
    for (int nd = 0; nd < 4; ++nd)
      vb[nd] = *(const bf16x8*)&vbase[(size_t)(nd*16 + lo)*2048 + j0 + hi*8];
#pragma unroll
    for (int m = 0; m < 2; ++m)
#pragma unroll
      for (int nd = 0; nd < 4; ++nd)
        o[m][nd] = __builtin_amdgcn_mfma_f32_16x16x32_bf16(pa[m], vb[nd], o[m][nd], 0,0,0);
  }

  // ---- merge 4 wave-partials ----
  __syncthreads();   // everyone done with plds slices
#pragma unroll
  for (int m = 0; m < 2; ++m)
#pragma unroll
    for (int nd = 0; nd < 4; ++nd)
#pragma unroll
      for (int r = 0; r < 4; ++r)
        Osh[(wv*64 + lane)*33 + (m*4 + nd)*4 + r] = o[m][nd][r];
  if (lo == 0) {
#pragma unroll
    for (int m = 0; m < 2; ++m)
#pragma unroll
      for (int r = 0; r < 4; ++r) {
        msh[wv][hi][m][r] = mrun[m][r];
        lsh[wv][hi][m][r] = lrun[m][r];
      }
  }
  __syncthreads();
  if (wv == 0) {
#pragma unroll
    for (int m = 0; m < 2; ++m)
#pragma unroll
      for (int r = 0; r < 4; ++r) {
        float M = msh[0][hi][m][r];
#pragma unroll
        for (int w = 1; w < 4; ++w) M = fmaxf(M, msh[w][hi][m][r]);
        float e[4], L = 0.f;
#pragma unroll
        for (int w = 0; w < 4; ++w) {
          e[w] = __expf(msh[w][hi][m][r] - M);
          L += e[w] * lsh[w][hi][m][r];
        }
        float rinv = 1.0f / L;
#pragma unroll
        for (int nd = 0; nd < 4; ++nd) {
          float s = 0.f;
#pragma unroll
          for (int w = 0; w < 4; ++w)
            s += e[w] * Osh[(w*64 + lane)*33 + (m*4 + nd)*4 + r];
          int row = q0 + m*16 + hi*4 + r;
          int col = hh*64 + nd*16 + lo;
          outb[(size_t)row*DIM + col] = (bf16)(s * rinv);
        }
      }
  }
}

// ---------------- small kernels ----------------
__global__ __launch_bounds__(256) void rope_init_kernel(float* __restrict__ ct, float* __restrict__ st) {
  int idx = blockIdx.x * 256 + threadIdx.x;
  if (idx >= SEQ * 32) return;
  int s = idx >> 5, i = idx & 31;
  float inv = powf(10000.0f, -(float)i / 32.0f);
  float f = (float)s * inv;
  ct[idx] = cosf(f);
  st[idx] = sinf(f);
}

__global__ __launch_bounds__(256) void cast_kernel(const float* __restrict__ src,
    bf16* __restrict__ dst, int perLayer, int dstStride, int dstOff, int L)
{
  int i = blockIdx.x * 256 + threadIdx.x;
  int e = i * 4;
  if (e >= perLayer * L) return;
  int l = e / perLayer;
  int o = e - l * perLayer;
  float4 v = *(const float4*)(src + e);
  bf16x4 b;
  b[0] = (bf16)v.x; b[1] = (bf16)v.y; b[2] = (bf16)v.z; b[3] = (bf16)v.w;
  *(bf16x4*)(dst + (size_t)l * dstStride + dstOff + o) = b;
}

__global__ __launch_bounds__(256) void embed_kernel(const int* __restrict__ tok,
    const float* __restrict__ emb, float* __restrict__ h)
{
  int s = blockIdx.x, t = threadIdx.x;
  int v = tok[s];
  ((float4*)(h + (size_t)s * DIM))[t] = ((const float4*)(emb + (size_t)v * DIM))[t];
}

__global__ __launch_bounds__(256) void rmsnorm_kernel(const float* __restrict__ h,
    const float* __restrict__ w, bf16* __restrict__ outb)
{
  int row = blockIdx.x, tid = threadIdx.x;
  float4 v = ((const float4*)(h + (size_t)row * DIM))[tid];
  float ss = v.x*v.x + v.y*v.y + v.z*v.z + v.w*v.w;
#pragma unroll
  for (int off = 1; off < 64; off <<= 1) ss += __shfl_xor(ss, off);
  __shared__ float red[4];
  if ((tid & 63) == 0) red[tid >> 6] = ss;
  __syncthreads();
  float tot = red[0] + red[1] + red[2] + red[3];
  float inv = rsqrtf(tot * (1.0f / DIM) + 1e-5f);
  float4 wv4 = ((const float4*)w)[tid];
  bf16x4 o;
  o[0] = (bf16)(v.x * inv * wv4.x);
  o[1] = (bf16)(v.y * inv * wv4.y);
  o[2] = (bf16)(v.z * inv * wv4.z);
  o[3] = (bf16)(v.w * inv * wv4.w);
  ((bf16x4*)(outb + (size_t)row * DIM))[tid] = o;
}

__global__ __launch_bounds__(256) void final_rms_kernel(const float* __restrict__ hrow,
    const float* __restrict__ w, float* __restrict__ fl)
{
  int tid = threadIdx.x;
  float4 v = ((const float4*)hrow)[tid];
  float ss = v.x*v.x + v.y*v.y + v.z*v.z + v.w*v.w;
#pragma unroll
  for (int off = 1; off < 64; off <<= 1) ss += __shfl_xor(ss, off);
  __shared__ float red[4];
  if ((tid & 63) == 0) red[tid >> 6] = ss;
  __syncthreads();
  float tot = red[0] + red[1] + red[2] + red[3];
  float inv = rsqrtf(tot * (1.0f / DIM) + 1e-5f);
  float4 wv4 = ((const float4*)w)[tid];
  float4 o;
  o.x = v.x * inv * wv4.x;
  o.y = v.y * inv * wv4.y;
  o.z = v.z * inv * wv4.z;
  o.w = v.w * inv * wv4.w;
  ((float4*)fl)[tid] = o;
}

// RoPE over q,k: each thread handles 8 contiguous bf16 (4 rot pairs) in one head.
__global__ __launch_bounds__(256) void rope_kernel(bf16* __restrict__ qkv,
    const float* __restrict__ ct, const float* __restrict__ st)
{
  int idx = blockIdx.x * 256 + threadIdx.x;
  if (idx >= SEQ * 128) return;
  int s = idx >> 7, rem = idx & 127;
  int h = rem >> 3, c8 = rem & 7;
  int d0 = c8 * 8, i0 = c8 * 4;
  float4 cv = *(const float4*)&ct[s*32 + i0];
  float4 sv = *(const float4*)&st[s*32 + i0];
  float c[4]  = {cv.x, cv.y, cv.z, cv.w};
  float sn[4] = {sv.x, sv.y, sv.z, sv.w};
  size_t base = (size_t)s * 3072 + h * 64 + d0;
#pragma unroll
  for (int part = 0; part < 2; ++part) {
    bf16x8 x = *(bf16x8*)&qkv[base + part * 1024];
    bf16x8 o;
#pragma unroll
    for (int p = 0; p < 4; ++p) {
      float xr = (float)x[2*p], xi = (float)x[2*p+1];
      o[2*p]   = (bf16)(xr * c[p] - xi * sn[p]);
      o[2*p+1] = (bf16)(xr * sn[p] + xi * c[p]);
    }
    *(bf16x8*)&qkv[base + part * 1024] = o;
  }
}

__global__ __launch_bounds__(256) void vtrans_kernel(const bf16* __restrict__ qkv,
    bf16* __restrict__ vt)
{
  int i = blockIdx.x * 256 + threadIdx.x;
  if (i >= SEQ * DIM) return;
  int d = i >> 11, j = i & 2047;
  vt[(size_t)d * SEQ + j] = qkv[(size_t)j * 3072 + 2048 + d];
}

__global__ __launch_bounds__(256) void silu_kernel(const bf16* __restrict__ ug,
    bf16* __restrict__ hb)
{
  int i = blockIdx.x * 256 + threadIdx.x;
  int s = i / 352, j8 = (i - s * 352) * 8;
  if (s >= SEQ) return;
  bf16x8 u = *(const bf16x8*)&ug[(size_t)s * 5632 + j8];
  bf16x8 g = *(const bf16x8*)&ug[(size_t)s * 5632 + 2816 + j8];
  bf16x8 o;
#pragma unroll
  for (int t = 0; t < 8; ++t) {
    float x = (float)u[t];
    float y = x / (1.f + __expf(-x)) * (float)g[t];
    o[t] = (bf16)y;
  }
  *(bf16x8*)&hb[(size_t)s * HID + j8] = o;
}

__global__ __launch_bounds__(64) void logits_kernel(const float* __restrict__ fl,
    const float* __restrict__ ow, float* __restrict__ outp)
{
  int v = blockIdx.x, lane = threadIdx.x;
  const float* row = ow + (size_t)v * DIM;
  float s = 0.f;
#pragma unroll
  for (int t = 0; t < 16; ++t) {
    int d = t * 64 + lane;
    s += fl[d] * row[d];
  }
#pragma unroll
  for (int off = 1; off < 64; off <<= 1) s += __shfl_xor(s, off);
  if (lane == 0) outp[v] = s;
}

// ---------------- host ----------------
extern "C" void kernel_launch(void* const* d_in, const int* in_sizes, int n_in,
                              void* d_out, int out_size, void* d_ws, size_t ws_size,
                              hipStream_t stream)
{
  const int*   tokens = (const int*)  d_in[0];
  const float* temb   = (const float*)d_in[1];
  const float* wq  = (const float*)d_in[2];
  const float* wk  = (const float*)d_in[3];
  const float* wvv = (const float*)d_in[4];
  const float* wo  = (const float*)d_in[5];
  const float* w1  = (const float*)d_in[6];
  const float* w2  = (const float*)d_in[7];
  const float* w3  = (const float*)d_in[8];
  const float* anw = (const float*)d_in[9];
  const float* fnw = (const float*)d_in[10];
  const float* finw= (const float*)d_in[11];
  const float* outw= (const float*)d_in[12];
  float* out = (float*)d_out;

  char* wsp = (char*)d_ws;
  size_t off = 0;
  auto take = [&](size_t bytes) -> void* {
    void* r = wsp + off;
    off += (bytes + 255) & ~(size_t)255;
    return r;
  };
  bf16* wqkv = (bf16*)take((size_t)NLAYER * 3072 * DIM * 2);
  bf16* wob  = (bf16*)take((size_t)NLAYER * DIM * DIM * 2);
  bf16* w13  = (bf16*)take((size_t)NLAYER * 2 * HID * DIM * 2);
  bf16* w2b  = (bf16*)take((size_t)NLAYER * DIM * HID * 2);
  float* h   = (float*)take((size_t)SEQ * DIM * 4);
  bf16* xn   = (bf16*)take((size_t)SEQ * DIM * 2);
  bf16* qkvb = (bf16*)take((size_t)SEQ * 3072 * 2);
  bf16* vtb  = (bf16*)take((size_t)DIM * SEQ * 2);
  bf16* attnb= (bf16*)take((size_t)SEQ * DIM * 2);
  bf16* ugb  = (bf16*)take((size_t)SEQ * 2 * HID * 2);
  bf16* hbb  = (bf16*)take((size_t)SEQ * HID * 2);
  float* ct  = (float*)take((size_t)SEQ * 32 * 4);
  float* st  = (float*)take((size_t)SEQ * 32 * 4);
  float* fl  = (float*)take((size_t)DIM * 4);

  rope_init_kernel<<<SEQ * 32 / 256, 256, 0, stream>>>(ct, st);

  const int PLd = DIM * DIM;        // 1048576
  const int PLh = HID * DIM;        // 2883584
  cast_kernel<<<PLd * NLAYER / 1024, 256, 0, stream>>>(wq,  wqkv, PLd, 3 * PLd, 0,       NLAYER);
  cast_kernel<<<PLd * NLAYER / 1024, 256, 0, stream>>>(wk,  wqkv, PLd, 3 * PLd, PLd,     NLAYER);
  cast_kernel<<<PLd * NLAYER / 1024, 256, 0, stream>>>(wvv, wqkv, PLd, 3 * PLd, 2 * PLd, NLAYER);
  cast_kernel<<<PLd * NLAYER / 1024, 256, 0, stream>>>(wo,  wob,  PLd, PLd,     0,       NLAYER);
  cast_kernel<<<PLh * NLAYER / 1024, 256, 0, stream>>>(w1,  w13,  PLh, 2 * PLh, 0,       NLAYER);
  cast_kernel<<<PLh * NLAYER / 1024, 256, 0, stream>>>(w3,  w13,  PLh, 2 * PLh, PLh,     NLAYER);
  cast_kernel<<<PLh * NLAYER / 1024, 256, 0, stream>>>(w2,  w2b,  PLh, PLh,     0,       NLAYER);

  embed_kernel<<<SEQ, 256, 0, stream>>>(tokens, temb, h);

  for (int l = 0; l < NLAYER; ++l) {
    const bf16* lwqkv = wqkv + (size_t)l * 3 * PLd;
    const bf16* lwo   = wob  + (size_t)l * PLd;
    const bf16* lw13  = w13  + (size_t)l * 2 * PLh;
    const bf16* lw2   = w2b  + (size_t)l * PLh;

    rmsnorm_kernel<<<SEQ, 256, 0, stream>>>(h, anw + l * DIM, xn);
    gemm_bt<0><<<dim3(24, 16), 256, 0, stream>>>(xn, lwqkv, qkvb, nullptr, nullptr, SEQ, 3072, DIM);
    rope_kernel<<<SEQ * 128 / 256, 256, 0, stream>>>(qkvb, ct, st);
    vtrans_kernel<<<SEQ * DIM / 256, 256, 0, stream>>>(qkvb, vtb);
    attn_kernel<<<dim3(16, 64), 256, 0, stream>>>(qkvb, vtb, attnb);
    gemm_bt<1><<<dim3(8, 16), 256, 0, stream>>>(attnb, lwo, nullptr, h, h, SEQ, DIM, DIM);
    rmsnorm_kernel<<<SEQ, 256, 0, stream>>>(h, fnw + l * DIM, xn);
    gemm_bt<0><<<dim3(44, 16), 256, 0, stream>>>(xn, lw13, ugb, nullptr, nullptr, SEQ, 2 * HID, DIM);
    silu_kernel<<<SEQ * HID / 8 / 256, 256, 0, stream>>>(ugb, hbb);
    gemm_bt<1><<<dim3(8, 16), 256, 0, stream>>>(hbb, lw2, nullptr, h, h, SEQ, DIM, HID);
  }

  final_rms_kernel<<<1, 256, 0, stream>>>(h + (size_t)(SEQ - 1) * DIM, finw, fl);
  logits_kernel<<<256, 64, 0, stream>>>(fl, outw, out);
}

// Round 4
// 1036.288 us; speedup vs baseline: 1.3537x; 1.1578x over previous
//
#include <hip/hip_runtime.h>
#include <stdint.h>

typedef __bf16 bf16;
typedef __bf16 bf16x4 __attribute__((ext_vector_type(4)));
typedef __bf16 bf16x8 __attribute__((ext_vector_type(8)));
typedef float f32x4 __attribute__((ext_vector_type(4)));

#define SEQ 2048
#define DIM 1024
#define NHEAD 16
#define HDIM 64
#define HID 2816
#define NLAYER 4

__device__ __forceinline__ void gload_lds16(const void* g, void* l) {
  __builtin_amdgcn_global_load_lds(
      (const __attribute__((address_space(1))) void*)g,
      (__attribute__((address_space(3))) void*)l, 16, 0, 0);
}

// ---------------- GEMM: C[M,N] = A[M,K] @ B[N,K]^T ----------------
// MODE 0: Cb[idx] = (bf16)acc.  MODE 1: Cf[idx] = R[idx] + acc (f32 residual).
// BM: 128 (2x2 waves of 64x64) or 64 (2x2 waves of 32x64).
template <int MODE, int BM>
__global__ __launch_bounds__(256) void gemm_bt(
    const bf16* __restrict__ A, const bf16* __restrict__ B,
    bf16* __restrict__ Cb, float* __restrict__ Cf, const float* R,
    int M, int N, int K)
{
  constexpr int MR = BM / 32;   // per-wave m-fragments
  __shared__ bf16 As[BM * 32];
  __shared__ bf16 Bs[128 * 32];
  const int tid  = threadIdx.x;
  const int wv   = tid >> 6;
  const int lane = tid & 63;
  const int lo = lane & 15, hi = lane >> 4;
  const int row0 = blockIdx.y * BM;
  const int col0 = blockIdx.x * 128;
  const int wr = (wv >> 1) * (BM / 2);
  const int wc = (wv & 1) * 64;

  f32x4 acc[MR][4];
  const f32x4 zero = {0.f, 0.f, 0.f, 0.f};
#pragma unroll
  for (int m = 0; m < MR; ++m)
#pragma unroll
    for (int n = 0; n < 4; ++n) acc[m][n] = zero;

  const bf16* ag = A + (size_t)(row0 + (tid >> 2)) * K + (tid & 3) * 8;
  const bf16* bg = B + (size_t)(col0 + (tid >> 2)) * K + (tid & 3) * 8;
  bf16* as0 = As + wv * 512;
  bf16* bs0 = Bs + wv * 512;

  for (int k0 = 0; k0 < K; k0 += 32) {
    gload_lds16(ag, as0);
    if constexpr (BM == 128) gload_lds16(ag + (size_t)64*K, as0 + 2048);
    gload_lds16(bg,                 bs0);
    gload_lds16(bg + (size_t)64*K,  bs0 + 2048);
    ag += 32; bg += 32;
    __syncthreads();
    bf16x8 af[MR], bfv[4];
#pragma unroll
    for (int m = 0; m < MR; ++m)
      af[m] = *(const bf16x8*)&As[(wr + m * 16 + lo) * 32 + hi * 8];
#pragma unroll
    for (int n = 0; n < 4; ++n)
      bfv[n] = *(const bf16x8*)&Bs[(wc + n * 16 + lo) * 32 + hi * 8];
#pragma unroll
    for (int m = 0; m < MR; ++m)
#pragma unroll
      for (int n = 0; n < 4; ++n)
        acc[m][n] = __builtin_amdgcn_mfma_f32_16x16x32_bf16(af[m], bfv[n], acc[m][n], 0, 0, 0);
    __syncthreads();
  }

#pragma unroll
  for (int m = 0; m < MR; ++m)
#pragma unroll
    for (int n = 0; n < 4; ++n)
#pragma unroll
      for (int r = 0; r < 4; ++r) {
        const int row = row0 + wr + m * 16 + hi * 4 + r;
        const int col = col0 + wc + n * 16 + lo;
        const size_t idx = (size_t)row * N + col;
        if (MODE == 0) Cb[idx] = (bf16)acc[m][n][r];
        else           Cf[idx] = R[idx] + acc[m][n][r];
      }
}

// ---------------- flash attention: 4-wave KV-split, KVBLK=64, defer-max ----------------
// P tile per wave: [32 q][64 k] bf16, stride 64 (128 B rows), XOR-swizzled
// byte ^= ((row&7)<<4)  (bijective within row; 16B-granule preserving).
__global__ __launch_bounds__(256) void attn_kernel(const bf16* __restrict__ qkv,
    const bf16* __restrict__ vt, bf16* __restrict__ outb)
{
  // Merge buffer (33.8 KB). First 16 KB aliased as per-wave swizzled P slices.
  __shared__ float Osh[4 * 64 * 33];
  __shared__ float msh[4][4][2][4];
  __shared__ float lsh[4][4][2][4];

  const int tid  = threadIdx.x;
  const int wv   = tid >> 6;
  const int lane = tid & 63;
  const int lo = lane & 15, hi = lane >> 4;
  const int hh = blockIdx.x;        // head fastest -> head's K/V pinned per XCD L2
  const int q0 = blockIdx.y * 32;

  char* pbase = (char*)Osh + wv * 4096;   // 4 KB per-wave P slice

  bf16x8 qf[2][2];
#pragma unroll
  for (int m = 0; m < 2; ++m)
#pragma unroll
    for (int kd = 0; kd < 2; ++kd)
      qf[m][kd] = *(const bf16x8*)&qkv[(size_t)(q0 + m*16 + lo)*3072 + hh*64 + kd*32 + hi*8];

  const f32x4 zero = {0.f,0.f,0.f,0.f};
  f32x4 o[2][4];
  float mrun[2][4], lrun[2][4];
#pragma unroll
  for (int m = 0; m < 2; ++m) {
#pragma unroll
    for (int nd = 0; nd < 4; ++nd) o[m][nd] = zero;
#pragma unroll
    for (int r = 0; r < 4; ++r) { mrun[m][r] = -1e30f; lrun[m][r] = 0.f; }
  }

  const bf16* kbase = qkv + 1024 + hh*64;
  const bf16* vbase = vt + (size_t)hh*64*2048;

  for (int t = 0; t < 8; ++t) {
    const int j0 = (wv + 4*t) * 64;
    // ---- QK^T over 64 k-rows ----
    f32x4 sa[2][4];
    __builtin_amdgcn_s_setprio(1);
#pragma unroll
    for (int n = 0; n < 4; ++n) {
      bf16x8 kf0 = *(const bf16x8*)&kbase[(size_t)(j0 + n*16 + lo)*3072 + hi*8];
      bf16x8 kf1 = *(const bf16x8*)&kbase[(size_t)(j0 + n*16 + lo)*3072 + 32 + hi*8];
      sa[0][n] = __builtin_amdgcn_mfma_f32_16x16x32_bf16(qf[0][0], kf0, zero, 0,0,0);
      sa[0][n] = __builtin_amdgcn_mfma_f32_16x16x32_bf16(qf[0][1], kf1, sa[0][n], 0,0,0);
      sa[1][n] = __builtin_amdgcn_mfma_f32_16x16x32_bf16(qf[1][0], kf0, zero, 0,0,0);
      sa[1][n] = __builtin_amdgcn_mfma_f32_16x16x32_bf16(qf[1][1], kf1, sa[1][n], 0,0,0);
    }
    __builtin_amdgcn_s_setprio(0);

    // ---- tile max (scaled), defer-max check ----
    float pmax[2][4];
    bool ok = true;
#pragma unroll
    for (int m = 0; m < 2; ++m)
#pragma unroll
      for (int r = 0; r < 4; ++r) {
        float mx = fmaxf(fmaxf(sa[m][0][r], sa[m][1][r]), fmaxf(sa[m][2][r], sa[m][3][r]));
#pragma unroll
        for (int off = 1; off < 16; off <<= 1) mx = fmaxf(mx, __shfl_xor(mx, off));
        mx *= 0.125f;
        pmax[m][r] = mx;
        ok = ok && (mx <= mrun[m][r] + 8.0f);
      }
    if (!__all(ok)) {
#pragma unroll
      for (int m = 0; m < 2; ++m)
#pragma unroll
        for (int r = 0; r < 4; ++r) {
          float mnew = fmaxf(mrun[m][r], pmax[m][r]);
          float corr = __expf(mrun[m][r] - mnew);
          mrun[m][r] = mnew;
          lrun[m][r] *= corr;
#pragma unroll
          for (int nd = 0; nd < 4; ++nd) o[m][nd][r] *= corr;
        }
    }

    // ---- P = exp(S*scale - m), row-sum, store transposed to swizzled LDS ----
#pragma unroll
    for (int m = 0; m < 2; ++m)
#pragma unroll
      for (int r = 0; r < 4; ++r) {
        float ps = 0.f;
        const float nm = mrun[m][r];
        const int q = m*16 + hi*4 + r;
        const int swz = (q & 7) << 4;
        char* prow = pbase + (q << 7);
#pragma unroll
        for (int n = 0; n < 4; ++n) {
          float p = __expf(fmaf(sa[m][n][r], 0.125f, -nm));
          ps += p;
          *(bf16*)(prow + ((((n*16 + lo) << 1)) ^ swz)) = (bf16)p;
        }
#pragma unroll
        for (int off = 1; off < 16; off <<= 1) ps += __shfl_xor(ps, off);
        lrun[m][r] += ps;
      }

    // ---- PV: O += P[32x64] @ V^T[64d x 64k]^T ----
    bf16x8 pa[2][2];
#pragma unroll
    for (int m = 0; m < 2; ++m)
#pragma unroll
      for (int kk = 0; kk < 2; ++kk) {
        const int row = m*16 + lo;
        const int addr = (row << 7) | (((kk << 6) | (hi << 4)) ^ (((row) & 7) << 4));
        pa[m][kk] = *(const bf16x8*)(pbase + addr);
      }
    __builtin_amdgcn_s_setprio(1);
#pragma unroll
    for (int nd = 0; nd < 4; ++nd) {
      bf16x8 vb0 = *(const bf16x8*)&vbase[(size_t)(nd*16 + lo)*2048 + j0 + hi*8];
      bf16x8 vb1 = *(const bf16x8*)&vbase[(size_t)(nd*16 + lo)*2048 + j0 + 32 + hi*8];
      o[0][nd] = __builtin_amdgcn_mfma_f32_16x16x32_bf16(pa[0][0], vb0, o[0][nd], 0,0,0);
      o[0][nd] = __builtin_amdgcn_mfma_f32_16x16x32_bf16(pa[0][1], vb1, o[0][nd], 0,0,0);
      o[1][nd] = __builtin_amdgcn_mfma_f32_16x16x32_bf16(pa[1][0], vb0, o[1][nd], 0,0,0);
      o[1][nd] = __builtin_amdgcn_mfma_f32_16x16x32_bf16(pa[1][1], vb1, o[1][nd], 0,0,0);
    }
    __builtin_amdgcn_s_setprio(0);
  }

  // ---- merge 4 wave-partials ----
  __syncthreads();   // everyone done with P slices
#pragma unroll
  for (int m = 0; m < 2; ++m)
#pragma unroll
    for (int nd = 0; nd < 4; ++nd)
#pragma unroll
      for (int r = 0; r < 4; ++r)
        Osh[(wv*64 + lane)*33 + (m*4 + nd)*4 + r] = o[m][nd][r];
  if (lo == 0) {
#pragma unroll
    for (int m = 0; m < 2; ++m)
#pragma unroll
      for (int r = 0; r < 4; ++r) {
        msh[wv][hi][m][r] = mrun[m][r];
        lsh[wv][hi][m][r] = lrun[m][r];
      }
  }
  __syncthreads();
  if (wv == 0) {
#pragma unroll
    for (int m = 0; m < 2; ++m)
#pragma unroll
      for (int r = 0; r < 4; ++r) {
        float M = msh[0][hi][m][r];
#pragma unroll
        for (int w = 1; w < 4; ++w) M = fmaxf(M, msh[w][hi][m][r]);
        float e[4], L = 0.f;
#pragma unroll
        for (int w = 0; w < 4; ++w) {
          e[w] = __expf(msh[w][hi][m][r] - M);
          L += e[w] * lsh[w][hi][m][r];
        }
        float rinv = 1.0f / L;
#pragma unroll
        for (int nd = 0; nd < 4; ++nd) {
          float s = 0.f;
#pragma unroll
          for (int w = 0; w < 4; ++w)
            s += e[w] * Osh[(w*64 + lane)*33 + (m*4 + nd)*4 + r];
          int row = q0 + m*16 + hi*4 + r;
          int col = hh*64 + nd*16 + lo;
          outb[(size_t)row*DIM + col] = (bf16)(s * rinv);
        }
      }
  }
}

// ---------------- small kernels ----------------
__global__ __launch_bounds__(256) void rope_init_kernel(float* __restrict__ ct, float* __restrict__ st) {
  int idx = blockIdx.x * 256 + threadIdx.x;
  if (idx >= SEQ * 32) return;
  int s = idx >> 5, i = idx & 31;
  float inv = powf(10000.0f, -(float)i / 32.0f);
  float f = (float)s * inv;
  ct[idx] = cosf(f);
  st[idx] = sinf(f);
}

__global__ __launch_bounds__(256) void cast_kernel(const float* __restrict__ src,
    bf16* __restrict__ dst, int perLayer, int dstStride, int dstOff, int L)
{
  int i = blockIdx.x * 256 + threadIdx.x;
  int e = i * 4;
  if (e >= perLayer * L) return;
  int l = e / perLayer;
  int o = e - l * perLayer;
  float4 v = *(const float4*)(src + e);
  bf16x4 b;
  b[0] = (bf16)v.x; b[1] = (bf16)v.y; b[2] = (bf16)v.z; b[3] = (bf16)v.w;
  *(bf16x4*)(dst + (size_t)l * dstStride + dstOff + o) = b;
}

__global__ __launch_bounds__(256) void embed_kernel(const int* __restrict__ tok,
    const float* __restrict__ emb, float* __restrict__ h)
{
  int s = blockIdx.x, t = threadIdx.x;
  int v = tok[s];
  ((float4*)(h + (size_t)s * DIM))[t] = ((const float4*)(emb + (size_t)v * DIM))[t];
}

__global__ __launch_bounds__(256) void rmsnorm_kernel(const float* __restrict__ h,
    const float* __restrict__ w, bf16* __restrict__ outb)
{
  int row = blockIdx.x, tid = threadIdx.x;
  float4 v = ((const float4*)(h + (size_t)row * DIM))[tid];
  float ss = v.x*v.x + v.y*v.y + v.z*v.z + v.w*v.w;
#pragma unroll
  for (int off = 1; off < 64; off <<= 1) ss += __shfl_xor(ss, off);
  __shared__ float red[4];
  if ((tid & 63) == 0) red[tid >> 6] = ss;
  __syncthreads();
  float tot = red[0] + red[1] + red[2] + red[3];
  float inv = rsqrtf(tot * (1.0f / DIM) + 1e-5f);
  float4 wv4 = ((const float4*)w)[tid];
  bf16x4 o;
  o[0] = (bf16)(v.x * inv * wv4.x);
  o[1] = (bf16)(v.y * inv * wv4.y);
  o[2] = (bf16)(v.z * inv * wv4.z);
  o[3] = (bf16)(v.w * inv * wv4.w);
  ((bf16x4*)(outb + (size_t)row * DIM))[tid] = o;
}

__global__ __launch_bounds__(256) void final_rms_kernel(const float* __restrict__ hrow,
    const float* __restrict__ w, float* __restrict__ fl)
{
  int tid = threadIdx.x;
  float4 v = ((const float4*)hrow)[tid];
  float ss = v.x*v.x + v.y*v.y + v.z*v.z + v.w*v.w;
#pragma unroll
  for (int off = 1; off < 64; off <<= 1) ss += __shfl_xor(ss, off);
  __shared__ float red[4];
  if ((tid & 63) == 0) red[tid >> 6] = ss;
  __syncthreads();
  float tot = red[0] + red[1] + red[2] + red[3];
  float inv = rsqrtf(tot * (1.0f / DIM) + 1e-5f);
  float4 wv4 = ((const float4*)w)[tid];
  float4 o;
  o.x = v.x * inv * wv4.x;
  o.y = v.y * inv * wv4.y;
  o.z = v.z * inv * wv4.z;
  o.w = v.w * inv * wv4.w;
  ((float4*)fl)[tid] = o;
}

// RoPE over q,k: each thread handles 8 contiguous bf16 (4 rot pairs) in one head.
__global__ __launch_bounds__(256) void rope_kernel(bf16* __restrict__ qkv,
    const float* __restrict__ ct, const float* __restrict__ st)
{
  int idx = blockIdx.x * 256 + threadIdx.x;
  if (idx >= SEQ * 128) return;
  int s = idx >> 7, rem = idx & 127;
  int h = rem >> 3, c8 = rem & 7;
  int d0 = c8 * 8, i0 = c8 * 4;
  float4 cv = *(const float4*)&ct[s*32 + i0];
  float4 sv = *(const float4*)&st[s*32 + i0];
  float c[4]  = {cv.x, cv.y, cv.z, cv.w};
  float sn[4] = {sv.x, sv.y, sv.z, sv.w};
  size_t base = (size_t)s * 3072 + h * 64 + d0;
#pragma unroll
  for (int part = 0; part < 2; ++part) {
    bf16x8 x = *(bf16x8*)&qkv[base + part * 1024];
    bf16x8 o;
#pragma unroll
    for (int p = 0; p < 4; ++p) {
      float xr = (float)x[2*p], xi = (float)x[2*p+1];
      o[2*p]   = (bf16)(xr * c[p] - xi * sn[p]);
      o[2*p+1] = (bf16)(xr * sn[p] + xi * c[p]);
    }
    *(bf16x8*)&qkv[base + part * 1024] = o;
  }
}

__global__ __launch_bounds__(256) void vtrans_kernel(const bf16* __restrict__ qkv,
    bf16* __restrict__ vt)
{
  int i = blockIdx.x * 256 + threadIdx.x;
  if (i >= SEQ * DIM) return;
  int d = i >> 11, j = i & 2047;
  vt[(size_t)d * SEQ + j] = qkv[(size_t)j * 3072 + 2048 + d];
}

__global__ __launch_bounds__(256) void silu_kernel(const bf16* __restrict__ ug,
    bf16* __restrict__ hb)
{
  int i = blockIdx.x * 256 + threadIdx.x;
  int s = i / 352, j8 = (i - s * 352) * 8;
  if (s >= SEQ) return;
  bf16x8 u = *(const bf16x8*)&ug[(size_t)s * 5632 + j8];
  bf16x8 g = *(const bf16x8*)&ug[(size_t)s * 5632 + 2816 + j8];
  bf16x8 o;
#pragma unroll
  for (int t = 0; t < 8; ++t) {
    float x = (float)u[t];
    float y = x / (1.f + __expf(-x)) * (float)g[t];
    o[t] = (bf16)y;
  }
  *(bf16x8*)&hb[(size_t)s * HID + j8] = o;
}

__global__ __launch_bounds__(64) void logits_kernel(const float* __restrict__ fl,
    const float* __restrict__ ow, float* __restrict__ outp)
{
  int v = blockIdx.x, lane = threadIdx.x;
  const float* row = ow + (size_t)v * DIM;
  float s = 0.f;
#pragma unroll
  for (int t = 0; t < 16; ++t) {
    int d = t * 64 + lane;
    s += fl[d] * row[d];
  }
#pragma unroll
  for (int off = 1; off < 64; off <<= 1) s += __shfl_xor(s, off);
  if (lane == 0) outp[v] = s;
}

// ---------------- host ----------------
extern "C" void kernel_launch(void* const* d_in, const int* in_sizes, int n_in,
                              void* d_out, int out_size, void* d_ws, size_t ws_size,
                              hipStream_t stream)
{
  const int*   tokens = (const int*)  d_in[0];
  const float* temb   = (const float*)d_in[1];
  const float* wq  = (const float*)d_in[2];
  const float* wk  = (const float*)d_in[3];
  const float* wvv = (const float*)d_in[4];
  const float* wo  = (const float*)d_in[5];
  const float* w1  = (const float*)d_in[6];
  const float* w2  = (const float*)d_in[7];
  const float* w3  = (const float*)d_in[8];
  const float* anw = (const float*)d_in[9];
  const float* fnw = (const float*)d_in[10];
  const float* finw= (const float*)d_in[11];
  const float* outw= (const float*)d_in[12];
  float* out = (float*)d_out;

  char* wsp = (char*)d_ws;
  size_t off = 0;
  auto take = [&](size_t bytes) -> void* {
    void* r = wsp + off;
    off += (bytes + 255) & ~(size_t)255;
    return r;
  };
  bf16* wqkv = (bf16*)take((size_t)NLAYER * 3072 * DIM * 2);
  bf16* wob  = (bf16*)take((size_t)NLAYER * DIM * DIM * 2);
  bf16* w13  = (bf16*)take((size_t)NLAYER * 2 * HID * DIM * 2);
  bf16* w2b  = (bf16*)take((size_t)NLAYER * DIM * HID * 2);
  float* h   = (float*)take((size_t)SEQ * DIM * 4);
  bf16* xn   = (bf16*)take((size_t)SEQ * DIM * 2);
  bf16* qkvb = (bf16*)take((size_t)SEQ * 3072 * 2);
  bf16* vtb  = (bf16*)take((size_t)DIM * SEQ * 2);
  bf16* attnb= (bf16*)take((size_t)SEQ * DIM * 2);
  bf16* ugb  = (bf16*)take((size_t)SEQ * 2 * HID * 2);
  bf16* hbb  = (bf16*)take((size_t)SEQ * HID * 2);
  float* ct  = (float*)take((size_t)SEQ * 32 * 4);
  float* st  = (float*)take((size_t)SEQ * 32 * 4);
  float* fl  = (float*)take((size_t)DIM * 4);

  rope_init_kernel<<<SEQ * 32 / 256, 256, 0, stream>>>(ct, st);

  const int PLd = DIM * DIM;        // 1048576
  const int PLh = HID * DIM;        // 2883584
  cast_kernel<<<PLd * NLAYER / 1024, 256, 0, stream>>>(wq,  wqkv, PLd, 3 * PLd, 0,       NLAYER);
  cast_kernel<<<PLd * NLAYER / 1024, 256, 0, stream>>>(wk,  wqkv, PLd, 3 * PLd, PLd,     NLAYER);
  cast_kernel<<<PLd * NLAYER / 1024, 256, 0, stream>>>(wvv, wqkv, PLd, 3 * PLd, 2 * PLd, NLAYER);
  cast_kernel<<<PLd * NLAYER / 1024, 256, 0, stream>>>(wo,  wob,  PLd, PLd,     0,       NLAYER);
  cast_kernel<<<PLh * NLAYER / 1024, 256, 0, stream>>>(w1,  w13,  PLh, 2 * PLh, 0,       NLAYER);
  cast_kernel<<<PLh * NLAYER / 1024, 256, 0, stream>>>(w3,  w13,  PLh, 2 * PLh, PLh,     NLAYER);
  cast_kernel<<<PLh * NLAYER / 1024, 256, 0, stream>>>(w2,  w2b,  PLh, PLh,     0,       NLAYER);

  embed_kernel<<<SEQ, 256, 0, stream>>>(tokens, temb, h);

  for (int l = 0; l < NLAYER; ++l) {
    const bf16* lwqkv = wqkv + (size_t)l * 3 * PLd;
    const bf16* lwo   = wob  + (size_t)l * PLd;
    const bf16* lw13  = w13  + (size_t)l * 2 * PLh;
    const bf16* lw2   = w2b  + (size_t)l * PLh;

    rmsnorm_kernel<<<SEQ, 256, 0, stream>>>(h, anw + l * DIM, xn);
    gemm_bt<0,128><<<dim3(24, 16), 256, 0, stream>>>(xn, lwqkv, qkvb, nullptr, nullptr, SEQ, 3072, DIM);
    rope_kernel<<<SEQ * 128 / 256, 256, 0, stream>>>(qkvb, ct, st);
    vtrans_kernel<<<SEQ * DIM / 256, 256, 0, stream>>>(qkvb, vtb);
    attn_kernel<<<dim3(16, 64), 256, 0, stream>>>(qkvb, vtb, attnb);
    gemm_bt<1,64><<<dim3(8, 32), 256, 0, stream>>>(attnb, lwo, nullptr, h, h, SEQ, DIM, DIM);
    rmsnorm_kernel<<<SEQ, 256, 0, stream>>>(h, fnw + l * DIM, xn);
    gemm_bt<0,128><<<dim3(44, 16), 256, 0, stream>>>(xn, lw13, ugb, nullptr, nullptr, SEQ, 2 * HID, DIM);
    silu_kernel<<<SEQ * HID / 8 / 256, 256, 0, stream>>>(ugb, hbb);
    gemm_bt<1,64><<<dim3(8, 32), 256, 0, stream>>>(hbb, lw2, nullptr, h, h, SEQ, DIM, HID);
  }

  final_rms_kernel<<<1, 256, 0, stream>>>(h + (size_t)(SEQ - 1) * DIM, finw, fl);
  logits_kernel<<<256, 64, 0, stream>>>(fl, outw, out);
}

// Round 5
// 1010.420 us; speedup vs baseline: 1.3884x; 1.0256x over previous
//
#include <hip/hip_runtime.h>
#include <stdint.h>

typedef __bf16 bf16;
typedef __bf16 bf16x4 __attribute__((ext_vector_type(4)));
typedef __bf16 bf16x8 __attribute__((ext_vector_type(8)));
typedef float f32x4 __attribute__((ext_vector_type(4)));

#define SEQ 2048
#define DIM 1024
#define NHEAD 16
#define HDIM 64
#define HID 2816
#define NLAYER 4

__device__ __forceinline__ void gload_lds16(const void* g, void* l) {
  __builtin_amdgcn_global_load_lds(
      (const __attribute__((address_space(1))) void*)g,
      (__attribute__((address_space(3))) void*)l, 16, 0, 0);
}

// ---------------- GEMM: C[M,N] = A[M,K] @ B[N,K]^T ----------------
// MODE 0: Cb[idx] = (bf16)acc.  MODE 1: Cf[idx] = R[idx] + acc (f32 residual).
// BM: 128 (2x2 waves of 64x64) or 64 (2x2 waves of 32x64).
template <int MODE, int BM>
__global__ __launch_bounds__(256) void gemm_bt(
    const bf16* __restrict__ A, const bf16* __restrict__ B,
    bf16* __restrict__ Cb, float* __restrict__ Cf, const float* R,
    int M, int N, int K)
{
  constexpr int MR = BM / 32;   // per-wave m-fragments
  __shared__ bf16 As[BM * 32];
  __shared__ bf16 Bs[128 * 32];
  const int tid  = threadIdx.x;
  const int wv   = tid >> 6;
  const int lane = tid & 63;
  const int lo = lane & 15, hi = lane >> 4;
  const int row0 = blockIdx.y * BM;
  const int col0 = blockIdx.x * 128;
  const int wr = (wv >> 1) * (BM / 2);
  const int wc = (wv & 1) * 64;

  f32x4 acc[MR][4];
  const f32x4 zero = {0.f, 0.f, 0.f, 0.f};
#pragma unroll
  for (int m = 0; m < MR; ++m)
#pragma unroll
    for (int n = 0; n < 4; ++n) acc[m][n] = zero;

  const bf16* ag = A + (size_t)(row0 + (tid >> 2)) * K + (tid & 3) * 8;
  const bf16* bg = B + (size_t)(col0 + (tid >> 2)) * K + (tid & 3) * 8;
  bf16* as0 = As + wv * 512;
  bf16* bs0 = Bs + wv * 512;

  for (int k0 = 0; k0 < K; k0 += 32) {
    gload_lds16(ag, as0);
    if constexpr (BM == 128) gload_lds16(ag + (size_t)64*K, as0 + 2048);
    gload_lds16(bg,                 bs0);
    gload_lds16(bg + (size_t)64*K,  bs0 + 2048);
    ag += 32; bg += 32;
    __syncthreads();
    bf16x8 af[MR], bfv[4];
#pragma unroll
    for (int m = 0; m < MR; ++m)
      af[m] = *(const bf16x8*)&As[(wr + m * 16 + lo) * 32 + hi * 8];
#pragma unroll
    for (int n = 0; n < 4; ++n)
      bfv[n] = *(const bf16x8*)&Bs[(wc + n * 16 + lo) * 32 + hi * 8];
#pragma unroll
    for (int m = 0; m < MR; ++m)
#pragma unroll
      for (int n = 0; n < 4; ++n)
        acc[m][n] = __builtin_amdgcn_mfma_f32_16x16x32_bf16(af[m], bfv[n], acc[m][n], 0, 0, 0);
    __syncthreads();
  }

#pragma unroll
  for (int m = 0; m < MR; ++m)
#pragma unroll
    for (int n = 0; n < 4; ++n)
#pragma unroll
      for (int r = 0; r < 4; ++r) {
        const int row = row0 + wr + m * 16 + hi * 4 + r;
        const int col = col0 + wc + n * 16 + lo;
        const size_t idx = (size_t)row * N + col;
        if (MODE == 0) Cb[idx] = (bf16)acc[m][n][r];
        else           Cf[idx] = R[idx] + acc[m][n][r];
      }
}

// ---------------- flash attention: 4-wave KV-split, KVBLK=64, defer-max,
// register-pipelined: K double-buffered (next tile prefetched at iter top),
// V issued at iter top and consumed after softmax (~500 cy cover). ----------------
__device__ __forceinline__ void attn_tile(
    const bf16* __restrict__ kbase, const bf16* __restrict__ vbase,
    char* pbase, const bf16x8 (&qf)[2][2],
    bf16x8 (&cur)[4][2], bf16x8 (&nxt)[4][2],
    f32x4 (&o)[2][4], float (&mrun)[2][4], float (&lrun)[2][4],
    int j0, int jn, int lo, int hi)
{
  const f32x4 zero = {0.f,0.f,0.f,0.f};
  // ---- V loads for CURRENT tile: issued now, used after softmax ----
  bf16x8 vc[4][2];
#pragma unroll
  for (int nd = 0; nd < 4; ++nd) {
    vc[nd][0] = *(const bf16x8*)&vbase[(size_t)(nd*16 + lo)*2048 + j0 + hi*8];
    vc[nd][1] = *(const bf16x8*)&vbase[(size_t)(nd*16 + lo)*2048 + j0 + 32 + hi*8];
  }
  // ---- NEXT tile K prefetch (consumed next iteration) ----
#pragma unroll
  for (int n = 0; n < 4; ++n) {
    nxt[n][0] = *(const bf16x8*)&kbase[(size_t)(jn + n*16 + lo)*3072 + hi*8];
    nxt[n][1] = *(const bf16x8*)&kbase[(size_t)(jn + n*16 + lo)*3072 + 32 + hi*8];
  }
  // ---- QK^T with already-resident K ----
  f32x4 sa[2][4];
  __builtin_amdgcn_s_setprio(1);
#pragma unroll
  for (int n = 0; n < 4; ++n) {
    sa[0][n] = __builtin_amdgcn_mfma_f32_16x16x32_bf16(qf[0][0], cur[n][0], zero, 0,0,0);
    sa[0][n] = __builtin_amdgcn_mfma_f32_16x16x32_bf16(qf[0][1], cur[n][1], sa[0][n], 0,0,0);
    sa[1][n] = __builtin_amdgcn_mfma_f32_16x16x32_bf16(qf[1][0], cur[n][0], zero, 0,0,0);
    sa[1][n] = __builtin_amdgcn_mfma_f32_16x16x32_bf16(qf[1][1], cur[n][1], sa[1][n], 0,0,0);
  }
  __builtin_amdgcn_s_setprio(0);

  // ---- tile max (scaled), defer-max check ----
  float pmax[2][4];
  bool ok = true;
#pragma unroll
  for (int m = 0; m < 2; ++m)
#pragma unroll
    for (int r = 0; r < 4; ++r) {
      float mx = fmaxf(fmaxf(sa[m][0][r], sa[m][1][r]), fmaxf(sa[m][2][r], sa[m][3][r]));
#pragma unroll
      for (int off = 1; off < 16; off <<= 1) mx = fmaxf(mx, __shfl_xor(mx, off));
      mx *= 0.125f;
      pmax[m][r] = mx;
      ok = ok && (mx <= mrun[m][r] + 8.0f);
    }
  if (!__all(ok)) {
#pragma unroll
    for (int m = 0; m < 2; ++m)
#pragma unroll
      for (int r = 0; r < 4; ++r) {
        float mnew = fmaxf(mrun[m][r], pmax[m][r]);
        float corr = __expf(mrun[m][r] - mnew);
        mrun[m][r] = mnew;
        lrun[m][r] *= corr;
#pragma unroll
        for (int nd = 0; nd < 4; ++nd) o[m][nd][r] *= corr;
      }
  }

  // ---- P = exp(S*scale - m), row-sum, store transposed to swizzled LDS ----
#pragma unroll
  for (int m = 0; m < 2; ++m)
#pragma unroll
    for (int r = 0; r < 4; ++r) {
      float ps = 0.f;
      const float nm = mrun[m][r];
      const int q = m*16 + hi*4 + r;
      const int swz = (q & 7) << 4;
      char* prow = pbase + (q << 7);
#pragma unroll
      for (int n = 0; n < 4; ++n) {
        float p = __expf(fmaf(sa[m][n][r], 0.125f, -nm));
        ps += p;
        *(bf16*)(prow + ((((n*16 + lo) << 1)) ^ swz)) = (bf16)p;
      }
#pragma unroll
      for (int off = 1; off < 16; off <<= 1) ps += __shfl_xor(ps, off);
      lrun[m][r] += ps;
    }

  // ---- PV: O += P[32x64] @ V^T ----
  bf16x8 pa[2][2];
#pragma unroll
  for (int m = 0; m < 2; ++m)
#pragma unroll
    for (int kk = 0; kk < 2; ++kk) {
      const int row = m*16 + lo;
      const int addr = (row << 7) | (((kk << 6) | (hi << 4)) ^ ((row & 7) << 4));
      pa[m][kk] = *(const bf16x8*)(pbase + addr);
    }
  __builtin_amdgcn_s_setprio(1);
#pragma unroll
  for (int nd = 0; nd < 4; ++nd) {
    o[0][nd] = __builtin_amdgcn_mfma_f32_16x16x32_bf16(pa[0][0], vc[nd][0], o[0][nd], 0,0,0);
    o[0][nd] = __builtin_amdgcn_mfma_f32_16x16x32_bf16(pa[0][1], vc[nd][1], o[0][nd], 0,0,0);
    o[1][nd] = __builtin_amdgcn_mfma_f32_16x16x32_bf16(pa[1][0], vc[nd][0], o[1][nd], 0,0,0);
    o[1][nd] = __builtin_amdgcn_mfma_f32_16x16x32_bf16(pa[1][1], vc[nd][1], o[1][nd], 0,0,0);
  }
  __builtin_amdgcn_s_setprio(0);
}

__global__ __launch_bounds__(256, 2) void attn_kernel(const bf16* __restrict__ qkv,
    const bf16* __restrict__ vt, bf16* __restrict__ outb)
{
  // Merge buffer (33.8 KB). First 16 KB aliased as per-wave swizzled P slices.
  __shared__ float Osh[4 * 64 * 33];
  __shared__ float msh[4][4][2][4];
  __shared__ float lsh[4][4][2][4];

  const int tid  = threadIdx.x;
  const int wv   = tid >> 6;
  const int lane = tid & 63;
  const int lo = lane & 15, hi = lane >> 4;
  const int hh = blockIdx.x;        // head fastest -> head's K/V pinned per XCD L2
  const int q0 = blockIdx.y * 32;

  char* pbase = (char*)Osh + wv * 4096;   // 4 KB per-wave P slice

  bf16x8 qf[2][2];
#pragma unroll
  for (int m = 0; m < 2; ++m)
#pragma unroll
    for (int kd = 0; kd < 2; ++kd)
      qf[m][kd] = *(const bf16x8*)&qkv[(size_t)(q0 + m*16 + lo)*3072 + hh*64 + kd*32 + hi*8];

  const f32x4 zero = {0.f,0.f,0.f,0.f};
  f32x4 o[2][4];
  float mrun[2][4], lrun[2][4];
#pragma unroll
  for (int m = 0; m < 2; ++m) {
#pragma unroll
    for (int nd = 0; nd < 4; ++nd) o[m][nd] = zero;
#pragma unroll
    for (int r = 0; r < 4; ++r) { mrun[m][r] = -1e30f; lrun[m][r] = 0.f; }
  }

  const bf16* kbase = qkv + 1024 + hh*64;
  const bf16* vbase = vt + (size_t)hh*64*2048;

  // ---- prologue: K tile 0 into ka ----
  bf16x8 ka[4][2], kb[4][2];
  {
    const int j0 = wv * 64;
#pragma unroll
    for (int n = 0; n < 4; ++n) {
      ka[n][0] = *(const bf16x8*)&kbase[(size_t)(j0 + n*16 + lo)*3072 + hi*8];
      ka[n][1] = *(const bf16x8*)&kbase[(size_t)(j0 + n*16 + lo)*3072 + 32 + hi*8];
    }
  }

  // ---- main loop: 8 tiles, ping-pong K buffers (static indexing) ----
  for (int t = 0; t < 8; t += 2) {
    attn_tile(kbase, vbase, pbase, qf, ka, kb, o, mrun, lrun,
              (wv + 4*t)*64,     ((wv + 4*(t+1)) & 31)*64, lo, hi);
    attn_tile(kbase, vbase, pbase, qf, kb, ka, o, mrun, lrun,
              (wv + 4*(t+1))*64, ((wv + 4*(t+2)) & 31)*64, lo, hi);
  }

  // ---- merge 4 wave-partials ----
  __syncthreads();   // everyone done with P slices
#pragma unroll
  for (int m = 0; m < 2; ++m)
#pragma unroll
    for (int nd = 0; nd < 4; ++nd)
#pragma unroll
      for (int r = 0; r < 4; ++r)
        Osh[(wv*64 + lane)*33 + (m*4 + nd)*4 + r] = o[m][nd][r];
  if (lo == 0) {
#pragma unroll
    for (int m = 0; m < 2; ++m)
#pragma unroll
      for (int r = 0; r < 4; ++r) {
        msh[wv][hi][m][r] = mrun[m][r];
        lsh[wv][hi][m][r] = lrun[m][r];
      }
  }
  __syncthreads();
  if (wv == 0) {
#pragma unroll
    for (int m = 0; m < 2; ++m)
#pragma unroll
      for (int r = 0; r < 4; ++r) {
        float M = msh[0][hi][m][r];
#pragma unroll
        for (int w = 1; w < 4; ++w) M = fmaxf(M, msh[w][hi][m][r]);
        float e[4], L = 0.f;
#pragma unroll
        for (int w = 0; w < 4; ++w) {
          e[w] = __expf(msh[w][hi][m][r] - M);
          L += e[w] * lsh[w][hi][m][r];
        }
        float rinv = 1.0f / L;
#pragma unroll
        for (int nd = 0; nd < 4; ++nd) {
          float s = 0.f;
#pragma unroll
          for (int w = 0; w < 4; ++w)
            s += e[w] * Osh[(w*64 + lane)*33 + (m*4 + nd)*4 + r];
          int row = q0 + m*16 + hi*4 + r;
          int col = hh*64 + nd*16 + lo;
          outb[(size_t)row*DIM + col] = (bf16)(s * rinv);
        }
      }
  }
}

// ---------------- small kernels ----------------
__global__ __launch_bounds__(256) void rope_init_kernel(float* __restrict__ ct, float* __restrict__ st) {
  int idx = blockIdx.x * 256 + threadIdx.x;
  if (idx >= SEQ * 32) return;
  int s = idx >> 5, i = idx & 31;
  float inv = powf(10000.0f, -(float)i / 32.0f);
  float f = (float)s * inv;
  ct[idx] = cosf(f);
  st[idx] = sinf(f);
}

__global__ __launch_bounds__(256) void cast_kernel(const float* __restrict__ src,
    bf16* __restrict__ dst, int perLayer, int dstStride, int dstOff, int L)
{
  int i = blockIdx.x * 256 + threadIdx.x;
  int e = i * 4;
  if (e >= perLayer * L) return;
  int l = e / perLayer;
  int o = e - l * perLayer;
  float4 v = *(const float4*)(src + e);
  bf16x4 b;
  b[0] = (bf16)v.x; b[1] = (bf16)v.y; b[2] = (bf16)v.z; b[3] = (bf16)v.w;
  *(bf16x4*)(dst + (size_t)l * dstStride + dstOff + o) = b;
}

__global__ __launch_bounds__(256) void embed_kernel(const int* __restrict__ tok,
    const float* __restrict__ emb, float* __restrict__ h)
{
  int s = blockIdx.x, t = threadIdx.x;
  int v = tok[s];
  ((float4*)(h + (size_t)s * DIM))[t] = ((const float4*)(emb + (size_t)v * DIM))[t];
}

__global__ __launch_bounds__(256) void rmsnorm_kernel(const float* __restrict__ h,
    const float* __restrict__ w, bf16* __restrict__ outb)
{
  int row = blockIdx.x, tid = threadIdx.x;
  float4 v = ((const float4*)(h + (size_t)row * DIM))[tid];
  float ss = v.x*v.x + v.y*v.y + v.z*v.z + v.w*v.w;
#pragma unroll
  for (int off = 1; off < 64; off <<= 1) ss += __shfl_xor(ss, off);
  __shared__ float red[4];
  if ((tid & 63) == 0) red[tid >> 6] = ss;
  __syncthreads();
  float tot = red[0] + red[1] + red[2] + red[3];
  float inv = rsqrtf(tot * (1.0f / DIM) + 1e-5f);
  float4 wv4 = ((const float4*)w)[tid];
  bf16x4 o;
  o[0] = (bf16)(v.x * inv * wv4.x);
  o[1] = (bf16)(v.y * inv * wv4.y);
  o[2] = (bf16)(v.z * inv * wv4.z);
  o[3] = (bf16)(v.w * inv * wv4.w);
  ((bf16x4*)(outb + (size_t)row * DIM))[tid] = o;
}

__global__ __launch_bounds__(256) void final_rms_kernel(const float* __restrict__ hrow,
    const float* __restrict__ w, float* __restrict__ fl)
{
  int tid = threadIdx.x;
  float4 v = ((const float4*)hrow)[tid];
  float ss = v.x*v.x + v.y*v.y + v.z*v.z + v.w*v.w;
#pragma unroll
  for (int off = 1; off < 64; off <<= 1) ss += __shfl_xor(ss, off);
  __shared__ float red[4];
  if ((tid & 63) == 0) red[tid >> 6] = ss;
  __syncthreads();
  float tot = red[0] + red[1] + red[2] + red[3];
  float inv = rsqrtf(tot * (1.0f / DIM) + 1e-5f);
  float4 wv4 = ((const float4*)w)[tid];
  float4 o;
  o.x = v.x * inv * wv4.x;
  o.y = v.y * inv * wv4.y;
  o.z = v.z * inv * wv4.z;
  o.w = v.w * inv * wv4.w;
  ((float4*)fl)[tid] = o;
}

// RoPE over q,k: each thread handles 8 contiguous bf16 (4 rot pairs) in one head.
__global__ __launch_bounds__(256) void rope_kernel(bf16* __restrict__ qkv,
    const float* __restrict__ ct, const float* __restrict__ st)
{
  int idx = blockIdx.x * 256 + threadIdx.x;
  if (idx >= SEQ * 128) return;
  int s = idx >> 7, rem = idx & 127;
  int h = rem >> 3, c8 = rem & 7;
  int d0 = c8 * 8, i0 = c8 * 4;
  float4 cv = *(const float4*)&ct[s*32 + i0];
  float4 sv = *(const float4*)&st[s*32 + i0];
  float c[4]  = {cv.x, cv.y, cv.z, cv.w};
  float sn[4] = {sv.x, sv.y, sv.z, sv.w};
  size_t base = (size_t)s * 3072 + h * 64 + d0;
#pragma unroll
  for (int part = 0; part < 2; ++part) {
    bf16x8 x = *(bf16x8*)&qkv[base + part * 1024];
    bf16x8 o;
#pragma unroll
    for (int p = 0; p < 4; ++p) {
      float xr = (float)x[2*p], xi = (float)x[2*p+1];
      o[2*p]   = (bf16)(xr * c[p] - xi * sn[p]);
      o[2*p+1] = (bf16)(xr * sn[p] + xi * c[p]);
    }
    *(bf16x8*)&qkv[base + part * 1024] = o;
  }
}

__global__ __launch_bounds__(256) void vtrans_kernel(const bf16* __restrict__ qkv,
    bf16* __restrict__ vt)
{
  int i = blockIdx.x * 256 + threadIdx.x;
  if (i >= SEQ * DIM) return;
  int d = i >> 11, j = i & 2047;
  vt[(size_t)d * SEQ + j] = qkv[(size_t)j * 3072 + 2048 + d];
}

__global__ __launch_bounds__(256) void silu_kernel(const bf16* __restrict__ ug,
    bf16* __restrict__ hb)
{
  int i = blockIdx.x * 256 + threadIdx.x;
  int s = i / 352, j8 = (i - s * 352) * 8;
  if (s >= SEQ) return;
  bf16x8 u = *(const bf16x8*)&ug[(size_t)s * 5632 + j8];
  bf16x8 g = *(const bf16x8*)&ug[(size_t)s * 5632 + 2816 + j8];
  bf16x8 o;
#pragma unroll
  for (int t = 0; t < 8; ++t) {
    float x = (float)u[t];
    float y = x / (1.f + __expf(-x)) * (float)g[t];
    o[t] = (bf16)y;
  }
  *(bf16x8*)&hb[(size_t)s * HID + j8] = o;
}

__global__ __launch_bounds__(64) void logits_kernel(const float* __restrict__ fl,
    const float* __restrict__ ow, float* __restrict__ outp)
{
  int v = blockIdx.x, lane = threadIdx.x;
  const float* row = ow + (size_t)v * DIM;
  float s = 0.f;
#pragma unroll
  for (int t = 0; t < 16; ++t) {
    int d = t * 64 + lane;
    s += fl[d] * row[d];
  }
#pragma unroll
  for (int off = 1; off < 64; off <<= 1) s += __shfl_xor(s, off);
  if (lane == 0) outp[v] = s;
}

// ---------------- host ----------------
extern "C" void kernel_launch(void* const* d_in, const int* in_sizes, int n_in,
                              void* d_out, int out_size, void* d_ws, size_t ws_size,
                              hipStream_t stream)
{
  const int*   tokens = (const int*)  d_in[0];
  const float* temb   = (const float*)d_in[1];
  const float* wq  = (const float*)d_in[2];
  const float* wk  = (const float*)d_in[3];
  const float* wvv = (const float*)d_in[4];
  const float* wo  = (const float*)d_in[5];
  const float* w1  = (const float*)d_in[6];
  const float* w2  = (const float*)d_in[7];
  const float* w3  = (const float*)d_in[8];
  const float* anw = (const float*)d_in[9];
  const float* fnw = (const float*)d_in[10];
  const float* finw= (const float*)d_in[11];
  const float* outw= (const float*)d_in[12];
  float* out = (float*)d_out;

  char* wsp = (char*)d_ws;
  size_t off = 0;
  auto take = [&](size_t bytes) -> void* {
    void* r = wsp + off;
    off += (bytes + 255) & ~(size_t)255;
    return r;
  };
  bf16* wqkv = (bf16*)take((size_t)NLAYER * 3072 * DIM * 2);
  bf16* wob  = (bf16*)take((size_t)NLAYER * DIM * DIM * 2);
  bf16* w13  = (bf16*)take((size_t)NLAYER * 2 * HID * DIM * 2);
  bf16* w2b  = (bf16*)take((size_t)NLAYER * DIM * HID * 2);
  float* h   = (float*)take((size_t)SEQ * DIM * 4);
  bf16* xn   = (bf16*)take((size_t)SEQ * DIM * 2);
  bf16* qkvb = (bf16*)take((size_t)SEQ * 3072 * 2);
  bf16* vtb  = (bf16*)take((size_t)DIM * SEQ * 2);
  bf16* attnb= (bf16*)take((size_t)SEQ * DIM * 2);
  bf16* ugb  = (bf16*)take((size_t)SEQ * 2 * HID * 2);
  bf16* hbb  = (bf16*)take((size_t)SEQ * HID * 2);
  float* ct  = (float*)take((size_t)SEQ * 32 * 4);
  float* st  = (float*)take((size_t)SEQ * 32 * 4);
  float* fl  = (float*)take((size_t)DIM * 4);

  rope_init_kernel<<<SEQ * 32 / 256, 256, 0, stream>>>(ct, st);

  const int PLd = DIM * DIM;        // 1048576
  const int PLh = HID * DIM;        // 2883584
  cast_kernel<<<PLd * NLAYER / 1024, 256, 0, stream>>>(wq,  wqkv, PLd, 3 * PLd, 0,       NLAYER);
  cast_kernel<<<PLd * NLAYER / 1024, 256, 0, stream>>>(wk,  wqkv, PLd, 3 * PLd, PLd,     NLAYER);
  cast_kernel<<<PLd * NLAYER / 1024, 256, 0, stream>>>(wvv, wqkv, PLd, 3 * PLd, 2 * PLd, NLAYER);
  cast_kernel<<<PLd * NLAYER / 1024, 256, 0, stream>>>(wo,  wob,  PLd, PLd,     0,       NLAYER);
  cast_kernel<<<PLh * NLAYER / 1024, 256, 0, stream>>>(w1,  w13,  PLh, 2 * PLh, 0,       NLAYER);
  cast_kernel<<<PLh * NLAYER / 1024, 256, 0, stream>>>(w3,  w13,  PLh, 2 * PLh, PLh,     NLAYER);
  cast_kernel<<<PLh * NLAYER / 1024, 256, 0, stream>>>(w2,  w2b,  PLh, PLh,     0,       NLAYER);

  embed_kernel<<<SEQ, 256, 0, stream>>>(tokens, temb, h);

  for (int l = 0; l < NLAYER; ++l) {
    const bf16* lwqkv = wqkv + (size_t)l * 3 * PLd;
    const bf16* lwo   = wob  + (size_t)l * PLd;
    const bf16* lw13  = w13  + (size_t)l * 2 * PLh;
    const bf16* lw2   = w2b  + (size_t)l * PLh;

    rmsnorm_kernel<<<SEQ, 256, 0, stream>>>(h, anw + l * DIM, xn);
    gemm_bt<0,128><<<dim3(24, 16), 256, 0, stream>>>(xn, lwqkv, qkvb, nullptr, nullptr, SEQ, 3072, DIM);
    rope_kernel<<<SEQ * 128 / 256, 256, 0, stream>>>(qkvb, ct, st);
    vtrans_kernel<<<SEQ * DIM / 256, 256, 0, stream>>>(qkvb, vtb);
    attn_kernel<<<dim3(16, 64), 256, 0, stream>>>(qkvb, vtb, attnb);
    gemm_bt<1,64><<<dim3(8, 32), 256, 0, stream>>>(attnb, lwo, nullptr, h, h, SEQ, DIM, DIM);
    rmsnorm_kernel<<<SEQ, 256, 0, stream>>>(h, fnw + l * DIM, xn);
    gemm_bt<0,128><<<dim3(44, 16), 256, 0, stream>>>(xn, lw13, ugb, nullptr, nullptr, SEQ, 2 * HID, DIM);
    silu_kernel<<<SEQ * HID / 8 / 256, 256, 0, stream>>>(ugb, hbb);
    gemm_bt<1,64><<<dim3(8, 32), 256, 0, stream>>>(hbb, lw2, nullptr, h, h, SEQ, DIM, HID);
  }

  final_rms_kernel<<<1, 256, 0, stream>>>(h + (size_t)(SEQ - 1) * DIM, finw, fl);
  logits_kernel<<<256, 64, 0, stream>>>(fl, outw, out);
}

// Round 6
// 966.596 us; speedup vs baseline: 1.4513x; 1.0453x over previous
//
#include <hip/hip_runtime.h>
#include <stdint.h>

typedef __bf16 bf16;
typedef __bf16 bf16x4 __attribute__((ext_vector_type(4)));
typedef __bf16 bf16x8 __attribute__((ext_vector_type(8)));
typedef float f32x4 __attribute__((ext_vector_type(4)));
typedef float f32x16 __attribute__((ext_vector_type(16)));

#define SEQ 2048
#define DIM 1024
#define NHEAD 16
#define HDIM 64
#define HID 2816
#define NLAYER 4

__device__ __forceinline__ void gload_lds16(const void* g, void* l) {
  __builtin_amdgcn_global_load_lds(
      (const __attribute__((address_space(1))) void*)g,
      (__attribute__((address_space(3))) void*)l, 16, 0, 0);
}

// ---------------- GEMM: C[M,N] = A[M,K] @ B[N,K]^T ----------------
// MODE 0: Cb[idx] = (bf16)acc.  MODE 1: Cf[idx] = R[idx] + acc (f32 residual).
// BM: 128 (2x2 waves of 64x64) or 64 (2x2 waves of 32x64).
template <int MODE, int BM>
__global__ __launch_bounds__(256) void gemm_bt(
    const bf16* __restrict__ A, const bf16* __restrict__ B,
    bf16* __restrict__ Cb, float* __restrict__ Cf, const float* R,
    int M, int N, int K)
{
  constexpr int MR = BM / 32;   // per-wave m-fragments
  __shared__ bf16 As[BM * 32];
  __shared__ bf16 Bs[128 * 32];
  const int tid  = threadIdx.x;
  const int wv   = tid >> 6;
  const int lane = tid & 63;
  const int lo = lane & 15, hi = lane >> 4;
  const int row0 = blockIdx.y * BM;
  const int col0 = blockIdx.x * 128;
  const int wr = (wv >> 1) * (BM / 2);
  const int wc = (wv & 1) * 64;

  f32x4 acc[MR][4];
  const f32x4 zero = {0.f, 0.f, 0.f, 0.f};
#pragma unroll
  for (int m = 0; m < MR; ++m)
#pragma unroll
    for (int n = 0; n < 4; ++n) acc[m][n] = zero;

  const bf16* ag = A + (size_t)(row0 + (tid >> 2)) * K + (tid & 3) * 8;
  const bf16* bg = B + (size_t)(col0 + (tid >> 2)) * K + (tid & 3) * 8;
  bf16* as0 = As + wv * 512;
  bf16* bs0 = Bs + wv * 512;

  for (int k0 = 0; k0 < K; k0 += 32) {
    gload_lds16(ag, as0);
    if constexpr (BM == 128) gload_lds16(ag + (size_t)64*K, as0 + 2048);
    gload_lds16(bg,                 bs0);
    gload_lds16(bg + (size_t)64*K,  bs0 + 2048);
    ag += 32; bg += 32;
    __syncthreads();
    bf16x8 af[MR], bfv[4];
#pragma unroll
    for (int m = 0; m < MR; ++m)
      af[m] = *(const bf16x8*)&As[(wr + m * 16 + lo) * 32 + hi * 8];
#pragma unroll
    for (int n = 0; n < 4; ++n)
      bfv[n] = *(const bf16x8*)&Bs[(wc + n * 16 + lo) * 32 + hi * 8];
#pragma unroll
    for (int m = 0; m < MR; ++m)
#pragma unroll
      for (int n = 0; n < 4; ++n)
        acc[m][n] = __builtin_amdgcn_mfma_f32_16x16x32_bf16(af[m], bfv[n], acc[m][n], 0, 0, 0);
    __syncthreads();
  }

#pragma unroll
  for (int m = 0; m < MR; ++m)
#pragma unroll
    for (int n = 0; n < 4; ++n)
#pragma unroll
      for (int r = 0; r < 4; ++r) {
        const int row = row0 + wr + m * 16 + hi * 4 + r;
        const int col = col0 + wc + n * 16 + lo;
        const size_t idx = (size_t)row * N + col;
        if (MODE == 0) Cb[idx] = (bf16)acc[m][n][r];
        else           Cf[idx] = R[idx] + acc[m][n][r];
      }
}

// ---------------- flash attention: swapped QK^T on 32x32x16 MFMA ----------------
// 4-wave KV-split, KVBLK=32. Lane (q5=lane&31, h=lane>>5).
// QK^T: S' = mfma(K,Q) -> lane holds S[k=crow(r,h)][q=q5], crow=(r&3)+8*(r>>2)+4*h.
// Softmax lane-local (1 shfl_xor(32) per reduce). P packed to bf16 in-register;
// PV B-frag built by exchanging the partner k-quad across lane-halves.
// PV: O' = mfma(V^T, P) -> O'[d][q]; merged via padded LDS.
__device__ __forceinline__ void attn_tile32(
    const bf16* __restrict__ kb, const bf16* __restrict__ vb,
    const bf16x8 (&qf)[4], bf16x8 (&kc)[4], bf16x8 (&kn)[4],
    f32x16& o0, f32x16& o1, float& m, float& lsum,
    int j0, int jn, int q5, int h)
{
  // V for current tile: issued now, consumed after softmax (latency cover)
  bf16x8 vf[2][2];
#pragma unroll
  for (int c = 0; c < 2; ++c)
#pragma unroll
    for (int dh = 0; dh < 2; ++dh)
      vf[c][dh] = *(const bf16x8*)&vb[(size_t)(dh*32 + q5)*2048 + j0 + c*16];
  // next-tile K prefetch
  {
    const bf16* kp = kb + (size_t)(jn + q5)*3072;
#pragma unroll
    for (int dc = 0; dc < 4; ++dc) kn[dc] = *(const bf16x8*)(kp + dc*16);
  }
  // QK^T (Q prescaled by 1/8)
  f32x16 s;
#pragma unroll
  for (int r = 0; r < 16; ++r) s[r] = 0.f;
  __builtin_amdgcn_s_setprio(1);
#pragma unroll
  for (int dc = 0; dc < 4; ++dc)
    s = __builtin_amdgcn_mfma_f32_32x32x16_bf16(kc[dc], qf[dc], s, 0, 0, 0);
  __builtin_amdgcn_s_setprio(0);

  // row max over k (16 in-lane + cross-half)
  float mx = s[0];
#pragma unroll
  for (int r = 1; r < 16; ++r) mx = fmaxf(mx, s[r]);
  mx = fmaxf(mx, __shfl_xor(mx, 32));
  if (!__all(mx <= m + 8.0f)) {           // defer-max (THR=8)
    float mnew = fmaxf(m, mx);
    float corr = __expf(m - mnew);
    m = mnew; lsum *= corr;
#pragma unroll
    for (int r = 0; r < 16; ++r) { o0[r] *= corr; o1[r] *= corr; }
  }
  float p[16]; float ps = 0.f;
#pragma unroll
  for (int r = 0; r < 16; ++r) { p[r] = __expf(s[r] - m); ps += p[r]; }
  ps += __shfl_xor(ps, 32);
  lsum += ps;

  // pack P quads: w[g][t] holds k = 8g + 4h + {2t, 2t+1}
  unsigned int w[4][2];
#pragma unroll
  for (int g = 0; g < 4; ++g)
#pragma unroll
    for (int t2 = 0; t2 < 2; ++t2) {
      union { bf16 b[2]; unsigned int u; } pk;
      pk.b[0] = (bf16)p[g*4 + 2*t2];
      pk.b[1] = (bf16)p[g*4 + 2*t2 + 1];
      w[g][t2] = pk.u;
    }

  // per 16-k chunk: assemble B-frag P[q][k=c*16+h*8+j] (own quad + partner quad)
#pragma unroll
  for (int c = 0; c < 2; ++c) {
    unsigned int keep0 = h ? w[2*c+1][0] : w[2*c][0];
    unsigned int keep1 = h ? w[2*c+1][1] : w[2*c][1];
    unsigned int send0 = h ? w[2*c][0]   : w[2*c+1][0];
    unsigned int send1 = h ? w[2*c][1]   : w[2*c+1][1];
    unsigned int r0 = __shfl_xor(send0, 32);
    unsigned int r1 = __shfl_xor(send1, 32);
    union { unsigned int u[4]; bf16x8 v; } pf;
    pf.u[0] = h ? r0 : keep0;
    pf.u[1] = h ? r1 : keep1;
    pf.u[2] = h ? keep0 : r0;
    pf.u[3] = h ? keep1 : r1;
    __builtin_amdgcn_s_setprio(1);
    o0 = __builtin_amdgcn_mfma_f32_32x32x16_bf16(vf[c][0], pf.v, o0, 0, 0, 0);
    o1 = __builtin_amdgcn_mfma_f32_32x32x16_bf16(vf[c][1], pf.v, o1, 0, 0, 0);
    __builtin_amdgcn_s_setprio(0);
  }
}

__global__ __launch_bounds__(256, 2) void attn_kernel(const bf16* __restrict__ qkv,
    const bf16* __restrict__ vt, bf16* __restrict__ outb)
{
  __shared__ float Osh[4][32][65];   // padded: conflict-free stash
  __shared__ float msh[4][32];
  __shared__ float lsh[4][32];

  const int tid = threadIdx.x;
  const int wv = tid >> 6;
  const int lane = tid & 63;
  const int q5 = lane & 31, h = lane >> 5;
  const int hh = blockIdx.x;        // head fastest -> head's K/V pinned per XCD L2
  const int q0 = blockIdx.y * 32;

  // Q fragment (B-operand rows), prescaled by 1/8 (exact in bf16)
  const bf16* qb = qkv + (size_t)(q0 + q5)*3072 + hh*64 + h*8;
  bf16x8 qf[4];
#pragma unroll
  for (int dc = 0; dc < 4; ++dc) {
    bf16x8 x = *(const bf16x8*)(qb + dc*16);
#pragma unroll
    for (int j = 0; j < 8; ++j) x[j] = (bf16)(0.125f * (float)x[j]);
    qf[dc] = x;
  }

  const bf16* kb = qkv + 1024 + hh*64 + h*8;
  const bf16* vb = vt + (size_t)hh*64*2048 + h*8;

  f32x16 o0, o1;
#pragma unroll
  for (int r = 0; r < 16; ++r) { o0[r] = 0.f; o1[r] = 0.f; }
  float m = -1e30f, lsum = 0.f;

  // prologue: K tile 0
  bf16x8 ka[4], ka2[4];
  {
    const bf16* kp = kb + (size_t)(wv*32 + q5)*3072;
#pragma unroll
    for (int dc = 0; dc < 4; ++dc) ka[dc] = *(const bf16x8*)(kp + dc*16);
  }

  // 16 tiles per wave, interleaved KV-split, ping-pong K buffers
  for (int t = 0; t < 16; t += 2) {
    attn_tile32(kb, vb, qf, ka, ka2, o0, o1, m, lsum,
                (wv + 4*t)*32,     ((wv + 4*(t+1)) & 63)*32, q5, h);
    attn_tile32(kb, vb, qf, ka2, ka, o0, o1, m, lsum,
                (wv + 4*(t+1))*32, ((wv + 4*(t+2)) & 63)*32, q5, h);
  }

  // stash wave partials: O'[d][q] -> Osh[wv][q][d]
#pragma unroll
  for (int r = 0; r < 16; ++r) {
    const int dr = (r & 3) + 8*(r >> 2) + 4*h;
    Osh[wv][q5][dr]      = o0[r];
    Osh[wv][q5][32 + dr] = o1[r];
  }
  if (h == 0) { msh[wv][q5] = m; lsh[wv][q5] = lsum; }
  __syncthreads();

  // merge 4 partials: thread -> (q = tid>>3, 8 d's at (tid&7)*8)
  const int q = tid >> 3, d0 = (tid & 7) * 8;
  float mm = fmaxf(fmaxf(msh[0][q], msh[1][q]), fmaxf(msh[2][q], msh[3][q]));
  float e0 = __expf(msh[0][q] - mm), e1 = __expf(msh[1][q] - mm),
        e2 = __expf(msh[2][q] - mm), e3 = __expf(msh[3][q] - mm);
  float L = e0*lsh[0][q] + e1*lsh[1][q] + e2*lsh[2][q] + e3*lsh[3][q];
  float rinv = 1.0f / L;
  bf16x8 outv;
#pragma unroll
  for (int j = 0; j < 8; ++j) {
    float sum = e0*Osh[0][q][d0+j] + e1*Osh[1][q][d0+j]
              + e2*Osh[2][q][d0+j] + e3*Osh[3][q][d0+j];
    outv[j] = (bf16)(sum * rinv);
  }
  *(bf16x8*)&outb[(size_t)(q0 + q)*DIM + hh*64 + d0] = outv;
}

// ---------------- small kernels ----------------
__global__ __launch_bounds__(256) void rope_init_kernel(float* __restrict__ ct, float* __restrict__ st) {
  int idx = blockIdx.x * 256 + threadIdx.x;
  if (idx >= SEQ * 32) return;
  int s = idx >> 5, i = idx & 31;
  float inv = powf(10000.0f, -(float)i / 32.0f);
  float f = (float)s * inv;
  ct[idx] = cosf(f);
  st[idx] = sinf(f);
}

__global__ __launch_bounds__(256) void cast_kernel(const float* __restrict__ src,
    bf16* __restrict__ dst, int perLayer, int dstStride, int dstOff, int L)
{
  int i = blockIdx.x * 256 + threadIdx.x;
  int e = i * 4;
  if (e >= perLayer * L) return;
  int l = e / perLayer;
  int o = e - l * perLayer;
  float4 v = *(const float4*)(src + e);
  bf16x4 b;
  b[0] = (bf16)v.x; b[1] = (bf16)v.y; b[2] = (bf16)v.z; b[3] = (bf16)v.w;
  *(bf16x4*)(dst + (size_t)l * dstStride + dstOff + o) = b;
}

__global__ __launch_bounds__(256) void embed_kernel(const int* __restrict__ tok,
    const float* __restrict__ emb, float* __restrict__ h)
{
  int s = blockIdx.x, t = threadIdx.x;
  int v = tok[s];
  ((float4*)(h + (size_t)s * DIM))[t] = ((const float4*)(emb + (size_t)v * DIM))[t];
}

__global__ __launch_bounds__(256) void rmsnorm_kernel(const float* __restrict__ h,
    const float* __restrict__ w, bf16* __restrict__ outb)
{
  int row = blockIdx.x, tid = threadIdx.x;
  float4 v = ((const float4*)(h + (size_t)row * DIM))[tid];
  float ss = v.x*v.x + v.y*v.y + v.z*v.z + v.w*v.w;
#pragma unroll
  for (int off = 1; off < 64; off <<= 1) ss += __shfl_xor(ss, off);
  __shared__ float red[4];
  if ((tid & 63) == 0) red[tid >> 6] = ss;
  __syncthreads();
  float tot = red[0] + red[1] + red[2] + red[3];
  float inv = rsqrtf(tot * (1.0f / DIM) + 1e-5f);
  float4 wv4 = ((const float4*)w)[tid];
  bf16x4 o;
  o[0] = (bf16)(v.x * inv * wv4.x);
  o[1] = (bf16)(v.y * inv * wv4.y);
  o[2] = (bf16)(v.z * inv * wv4.z);
  o[3] = (bf16)(v.w * inv * wv4.w);
  ((bf16x4*)(outb + (size_t)row * DIM))[tid] = o;
}

__global__ __launch_bounds__(256) void final_rms_kernel(const float* __restrict__ hrow,
    const float* __restrict__ w, float* __restrict__ fl)
{
  int tid = threadIdx.x;
  float4 v = ((const float4*)hrow)[tid];
  float ss = v.x*v.x + v.y*v.y + v.z*v.z + v.w*v.w;
#pragma unroll
  for (int off = 1; off < 64; off <<= 1) ss += __shfl_xor(ss, off);
  __shared__ float red[4];
  if ((tid & 63) == 0) red[tid >> 6] = ss;
  __syncthreads();
  float tot = red[0] + red[1] + red[2] + red[3];
  float inv = rsqrtf(tot * (1.0f / DIM) + 1e-5f);
  float4 wv4 = ((const float4*)w)[tid];
  float4 o;
  o.x = v.x * inv * wv4.x;
  o.y = v.y * inv * wv4.y;
  o.z = v.z * inv * wv4.z;
  o.w = v.w * inv * wv4.w;
  ((float4*)fl)[tid] = o;
}

// RoPE over q,k: each thread handles 8 contiguous bf16 (4 rot pairs) in one head.
__global__ __launch_bounds__(256) void rope_kernel(bf16* __restrict__ qkv,
    const float* __restrict__ ct, const float* __restrict__ st)
{
  int idx = blockIdx.x * 256 + threadIdx.x;
  if (idx >= SEQ * 128) return;
  int s = idx >> 7, rem = idx & 127;
  int h = rem >> 3, c8 = rem & 7;
  int d0 = c8 * 8, i0 = c8 * 4;
  float4 cv = *(const float4*)&ct[s*32 + i0];
  float4 sv = *(const float4*)&st[s*32 + i0];
  float c[4]  = {cv.x, cv.y, cv.z, cv.w};
  float sn[4] = {sv.x, sv.y, sv.z, sv.w};
  size_t base = (size_t)s * 3072 + h * 64 + d0;
#pragma unroll
  for (int part = 0; part < 2; ++part) {
    bf16x8 x = *(bf16x8*)&qkv[base + part * 1024];
    bf16x8 o;
#pragma unroll
    for (int p = 0; p < 4; ++p) {
      float xr = (float)x[2*p], xi = (float)x[2*p+1];
      o[2*p]   = (bf16)(xr * c[p] - xi * sn[p]);
      o[2*p+1] = (bf16)(xr * sn[p] + xi * c[p]);
    }
    *(bf16x8*)&qkv[base + part * 1024] = o;
  }
}

__global__ __launch_bounds__(256) void vtrans_kernel(const bf16* __restrict__ qkv,
    bf16* __restrict__ vt)
{
  int i = blockIdx.x * 256 + threadIdx.x;
  if (i >= SEQ * DIM) return;
  int d = i >> 11, j = i & 2047;
  vt[(size_t)d * SEQ + j] = qkv[(size_t)j * 3072 + 2048 + d];
}

__global__ __launch_bounds__(256) void silu_kernel(const bf16* __restrict__ ug,
    bf16* __restrict__ hb)
{
  int i = blockIdx.x * 256 + threadIdx.x;
  int s = i / 352, j8 = (i - s * 352) * 8;
  if (s >= SEQ) return;
  bf16x8 u = *(const bf16x8*)&ug[(size_t)s * 5632 + j8];
  bf16x8 g = *(const bf16x8*)&ug[(size_t)s * 5632 + 2816 + j8];
  bf16x8 o;
#pragma unroll
  for (int t = 0; t < 8; ++t) {
    float x = (float)u[t];
    float y = x / (1.f + __expf(-x)) * (float)g[t];
    o[t] = (bf16)y;
  }
  *(bf16x8*)&hb[(size_t)s * HID + j8] = o;
}

__global__ __launch_bounds__(64) void logits_kernel(const float* __restrict__ fl,
    const float* __restrict__ ow, float* __restrict__ outp)
{
  int v = blockIdx.x, lane = threadIdx.x;
  const float* row = ow + (size_t)v * DIM;
  float s = 0.f;
#pragma unroll
  for (int t = 0; t < 16; ++t) {
    int d = t * 64 + lane;
    s += fl[d] * row[d];
  }
#pragma unroll
  for (int off = 1; off < 64; off <<= 1) s += __shfl_xor(s, off);
  if (lane == 0) outp[v] = s;
}

// ---------------- host ----------------
extern "C" void kernel_launch(void* const* d_in, const int* in_sizes, int n_in,
                              void* d_out, int out_size, void* d_ws, size_t ws_size,
                              hipStream_t stream)
{
  const int*   tokens = (const int*)  d_in[0];
  const float* temb   = (const float*)d_in[1];
  const float* wq  = (const float*)d_in[2];
  const float* wk  = (const float*)d_in[3];
  const float* wvv = (const float*)d_in[4];
  const float* wo  = (const float*)d_in[5];
  const float* w1  = (const float*)d_in[6];
  const float* w2  = (const float*)d_in[7];
  const float* w3  = (const float*)d_in[8];
  const float* anw = (const float*)d_in[9];
  const float* fnw = (const float*)d_in[10];
  const float* finw= (const float*)d_in[11];
  const float* outw= (const float*)d_in[12];
  float* out = (float*)d_out;

  char* wsp = (char*)d_ws;
  size_t off = 0;
  auto take = [&](size_t bytes) -> void* {
    void* r = wsp + off;
    off += (bytes + 255) & ~(size_t)255;
    return r;
  };
  bf16* wqkv = (bf16*)take((size_t)NLAYER * 3072 * DIM * 2);
  bf16* wob  = (bf16*)take((size_t)NLAYER * DIM * DIM * 2);
  bf16* w13  = (bf16*)take((size_t)NLAYER * 2 * HID * DIM * 2);
  bf16* w2b  = (bf16*)take((size_t)NLAYER * DIM * HID * 2);
  float* h   = (float*)take((size_t)SEQ * DIM * 4);
  bf16* xn   = (bf16*)take((size_t)SEQ * DIM * 2);
  bf16* qkvb = (bf16*)take((size_t)SEQ * 3072 * 2);
  bf16* vtb  = (bf16*)take((size_t)DIM * SEQ * 2);
  bf16* attnb= (bf16*)take((size_t)SEQ * DIM * 2);
  bf16* ugb  = (bf16*)take((size_t)SEQ * 2 * HID * 2);
  bf16* hbb  = (bf16*)take((size_t)SEQ * HID * 2);
  float* ct  = (float*)take((size_t)SEQ * 32 * 4);
  float* st  = (float*)take((size_t)SEQ * 32 * 4);
  float* fl  = (float*)take((size_t)DIM * 4);

  rope_init_kernel<<<SEQ * 32 / 256, 256, 0, stream>>>(ct, st);

  const int PLd = DIM * DIM;        // 1048576
  const int PLh = HID * DIM;        // 2883584
  cast_kernel<<<PLd * NLAYER / 1024, 256, 0, stream>>>(wq,  wqkv, PLd, 3 * PLd, 0,       NLAYER);
  cast_kernel<<<PLd * NLAYER / 1024, 256, 0, stream>>>(wk,  wqkv, PLd, 3 * PLd, PLd,     NLAYER);
  cast_kernel<<<PLd * NLAYER / 1024, 256, 0, stream>>>(wvv, wqkv, PLd, 3 * PLd, 2 * PLd, NLAYER);
  cast_kernel<<<PLd * NLAYER / 1024, 256, 0, stream>>>(wo,  wob,  PLd, PLd,     0,       NLAYER);
  cast_kernel<<<PLh * NLAYER / 1024, 256, 0, stream>>>(w1,  w13,  PLh, 2 * PLh, 0,       NLAYER);
  cast_kernel<<<PLh * NLAYER / 1024, 256, 0, stream>>>(w3,  w13,  PLh, 2 * PLh, PLh,     NLAYER);
  cast_kernel<<<PLh * NLAYER / 1024, 256, 0, stream>>>(w2,  w2b,  PLh, PLh,     0,       NLAYER);

  embed_kernel<<<SEQ, 256, 0, stream>>>(tokens, temb, h);

  for (int l = 0; l < NLAYER; ++l) {
    const bf16* lwqkv = wqkv + (size_t)l * 3 * PLd;
    const bf16* lwo   = wob  + (size_t)l * PLd;
    const bf16* lw13  = w13  + (size_t)l * 2 * PLh;
    const bf16* lw2   = w2b  + (size_t)l * PLh;

    rmsnorm_kernel<<<SEQ, 256, 0, stream>>>(h, anw + l * DIM, xn);
    gemm_bt<0,128><<<dim3(24, 16), 256, 0, stream>>>(xn, lwqkv, qkvb, nullptr, nullptr, SEQ, 3072, DIM);
    rope_kernel<<<SEQ * 128 / 256, 256, 0, stream>>>(qkvb, ct, st);
    vtrans_kernel<<<SEQ * DIM / 256, 256, 0, stream>>>(qkvb, vtb);
    attn_kernel<<<dim3(16, 64), 256, 0, stream>>>(qkvb, vtb, attnb);
    gemm_bt<1,64><<<dim3(8, 32), 256, 0, stream>>>(attnb, lwo, nullptr, h, h, SEQ, DIM, DIM);
    rmsnorm_kernel<<<SEQ, 256, 0, stream>>>(h, fnw + l * DIM, xn);
    gemm_bt<0,128><<<dim3(44, 16), 256, 0, stream>>>(xn, lw13, ugb, nullptr, nullptr, SEQ, 2 * HID, DIM);
    silu_kernel<<<SEQ * HID / 8 / 256, 256, 0, stream>>>(ugb, hbb);
    gemm_bt<1,64><<<dim3(8, 32), 256, 0, stream>>>(hbb, lw2, nullptr, h, h, SEQ, DIM, HID);
  }

  final_rms_kernel<<<1, 256, 0, stream>>>(h + (size_t)(SEQ - 1) * DIM, finw, fl);
  logits_kernel<<<256, 64, 0, stream>>>(fl, outw, out);
}

// Round 7
// 890.754 us; speedup vs baseline: 1.5749x; 1.0851x over previous
//
#include <hip/hip_runtime.h>
#include <stdint.h>

typedef __bf16 bf16;
typedef __bf16 bf16x4 __attribute__((ext_vector_type(4)));
typedef __bf16 bf16x8 __attribute__((ext_vector_type(8)));
typedef float f32x4 __attribute__((ext_vector_type(4)));
typedef float f32x16 __attribute__((ext_vector_type(16)));

#define SEQ 2048
#define DIM 1024
#define NHEAD 16
#define HDIM 64
#define HID 2816
#define NLAYER 4

__device__ __forceinline__ void gload_lds16(const void* g, void* l) {
  __builtin_amdgcn_global_load_lds(
      (const __attribute__((address_space(1))) void*)g,
      (__attribute__((address_space(3))) void*)l, 16, 0, 0);
}

// ---------------- GEMM: C[M,N] = A[M,K] @ B[N,K]^T ----------------
// 2-phase double-buffered staging: stage tile k+1 while MFMA'ing tile k,
// ONE barrier per K-step (vs 2 in the 1-phase form). Regime: low blocks/CU
// where no co-resident block hides the stage drain.
// MODE 0: Cb[idx] = (bf16)acc.  MODE 1: Cf[idx] = R[idx] + acc (f32 residual).
template <int MODE, int BM, int BN>
__global__ __launch_bounds__(256) void gemm_bt(
    const bf16* __restrict__ A, const bf16* __restrict__ B,
    bf16* __restrict__ Cb, float* __restrict__ Cf, const float* R,
    int M, int N, int K)
{
  constexpr int MR = BM / 32;       // per-wave m-fragments (16-row)
  constexpr int NR = BN / 32;       // per-wave n-fragments
  constexpr int LA = BM / 64;       // gloads per thread for A (1 or 2)
  constexpr int LB = BN / 64;
  __shared__ bf16 As[2 * BM * 32];
  __shared__ bf16 Bs[2 * BN * 32];
  const int tid  = threadIdx.x;
  const int wv   = tid >> 6;
  const int lane = tid & 63;
  const int lo = lane & 15, hi = lane >> 4;
  const int row0 = blockIdx.y * BM;
  const int col0 = blockIdx.x * BN;
  const int wr = (wv >> 1) * (BM / 2);
  const int wc = (wv & 1) * (BN / 2);

  f32x4 acc[MR][NR];
  const f32x4 zero = {0.f, 0.f, 0.f, 0.f};
#pragma unroll
  for (int m = 0; m < MR; ++m)
#pragma unroll
    for (int n = 0; n < NR; ++n) acc[m][n] = zero;

  const bf16* ag = A + (size_t)(row0 + (tid >> 2)) * K + (tid & 3) * 8;
  const bf16* bg = B + (size_t)(col0 + (tid >> 2)) * K + (tid & 3) * 8;

  auto stage = [&](int buf, int k) {
#pragma unroll
    for (int i = 0; i < LA; ++i)
      gload_lds16(ag + k + (size_t)i*64*K, &As[buf*BM*32 + i*2048 + wv*512]);
#pragma unroll
    for (int i = 0; i < LB; ++i)
      gload_lds16(bg + k + (size_t)i*64*K, &Bs[buf*BN*32 + i*2048 + wv*512]);
  };
  auto compute = [&](int buf) {
    bf16x8 af[MR], bfv[NR];
#pragma unroll
    for (int m = 0; m < MR; ++m)
      af[m] = *(const bf16x8*)&As[buf*BM*32 + (wr + m*16 + lo)*32 + hi*8];
#pragma unroll
    for (int n = 0; n < NR; ++n)
      bfv[n] = *(const bf16x8*)&Bs[buf*BN*32 + (wc + n*16 + lo)*32 + hi*8];
#pragma unroll
    for (int m = 0; m < MR; ++m)
#pragma unroll
      for (int n = 0; n < NR; ++n)
        acc[m][n] = __builtin_amdgcn_mfma_f32_16x16x32_bf16(af[m], bfv[n], acc[m][n], 0, 0, 0);
  };

  // prologue
  stage(0, 0);
  __syncthreads();
  // main loop: 2 K-steps (64 cols) per iteration, static ping-pong buffers.
  // K is a multiple of 64 for all call sites (1024, 2816).
  for (int k0 = 0; k0 < K; k0 += 64) {
    stage(1, k0 + 32);                 // overlap with compute(0)
    compute(0);
    __syncthreads();                   // drains stage(1) vmcnt + ds reads
    if (k0 + 64 < K) stage(0, k0 + 64);
    compute(1);
    __syncthreads();
  }

#pragma unroll
  for (int m = 0; m < MR; ++m)
#pragma unroll
    for (int n = 0; n < NR; ++n)
#pragma unroll
      for (int r = 0; r < 4; ++r) {
        const int row = row0 + wr + m * 16 + hi * 4 + r;
        const int col = col0 + wc + n * 16 + lo;
        const size_t idx = (size_t)row * N + col;
        if (MODE == 0) Cb[idx] = (bf16)acc[m][n][r];
        else           Cf[idx] = R[idx] + acc[m][n][r];
      }
}

// ---------------- flash attention: swapped QK^T on 32x32x16 MFMA ----------------
// 4-wave KV-split, KVBLK=32. Lane (q5=lane&31, h=lane>>5).
// QK^T: S' = mfma(K,Q) -> lane holds S[k=crow(r,h)][q=q5], crow=(r&3)+8*(r>>2)+4*h.
// Softmax lane-local (1 shfl_xor(32) per reduce). P packed to bf16 in-register;
// PV B-frag built by exchanging the partner k-quad across lane-halves.
// PV: O' = mfma(V^T, P) -> O'[d][q]; merged via padded LDS.
__device__ __forceinline__ void attn_tile32(
    const bf16* __restrict__ kb, const bf16* __restrict__ vb,
    const bf16x8 (&qf)[4], bf16x8 (&kc)[4], bf16x8 (&kn)[4],
    f32x16& o0, f32x16& o1, float& m, float& lsum,
    int j0, int jn, int q5, int h)
{
  // V for current tile: issued now, consumed after softmax (latency cover)
  bf16x8 vf[2][2];
#pragma unroll
  for (int c = 0; c < 2; ++c)
#pragma unroll
    for (int dh = 0; dh < 2; ++dh)
      vf[c][dh] = *(const bf16x8*)&vb[(size_t)(dh*32 + q5)*2048 + j0 + c*16];
  // next-tile K prefetch
  {
    const bf16* kp = kb + (size_t)(jn + q5)*3072;
#pragma unroll
    for (int dc = 0; dc < 4; ++dc) kn[dc] = *(const bf16x8*)(kp + dc*16);
  }
  // QK^T (Q prescaled by 1/8)
  f32x16 s;
#pragma unroll
  for (int r = 0; r < 16; ++r) s[r] = 0.f;
  __builtin_amdgcn_s_setprio(1);
#pragma unroll
  for (int dc = 0; dc < 4; ++dc)
    s = __builtin_amdgcn_mfma_f32_32x32x16_bf16(kc[dc], qf[dc], s, 0, 0, 0);
  __builtin_amdgcn_s_setprio(0);

  // row max over k (16 in-lane + cross-half)
  float mx = s[0];
#pragma unroll
  for (int r = 1; r < 16; ++r) mx = fmaxf(mx, s[r]);
  mx = fmaxf(mx, __shfl_xor(mx, 32));
  if (!__all(mx <= m + 8.0f)) {           // defer-max (THR=8)
    float mnew = fmaxf(m, mx);
    float corr = __expf(m - mnew);
    m = mnew; lsum *= corr;
#pragma unroll
    for (int r = 0; r < 16; ++r) { o0[r] *= corr; o1[r] *= corr; }
  }
  float p[16]; float ps = 0.f;
#pragma unroll
  for (int r = 0; r < 16; ++r) { p[r] = __expf(s[r] - m); ps += p[r]; }
  ps += __shfl_xor(ps, 32);
  lsum += ps;

  // pack P quads: w[g][t] holds k = 8g + 4h + {2t, 2t+1}
  unsigned int w[4][2];
#pragma unroll
  for (int g = 0; g < 4; ++g)
#pragma unroll
    for (int t2 = 0; t2 < 2; ++t2) {
      union { bf16 b[2]; unsigned int u; } pk;
      pk.b[0] = (bf16)p[g*4 + 2*t2];
      pk.b[1] = (bf16)p[g*4 + 2*t2 + 1];
      w[g][t2] = pk.u;
    }

  // per 16-k chunk: assemble B-frag P[q][k=c*16+h*8+j] (own quad + partner quad)
#pragma unroll
  for (int c = 0; c < 2; ++c) {
    unsigned int keep0 = h ? w[2*c+1][0] : w[2*c][0];
    unsigned int keep1 = h ? w[2*c+1][1] : w[2*c][1];
    unsigned int send0 = h ? w[2*c][0]   : w[2*c+1][0];
    unsigned int send1 = h ? w[2*c][1]   : w[2*c+1][1];
    unsigned int r0 = __shfl_xor(send0, 32);
    unsigned int r1 = __shfl_xor(send1, 32);
    union { unsigned int u[4]; bf16x8 v; } pf;
    pf.u[0] = h ? r0 : keep0;
    pf.u[1] = h ? r1 : keep1;
    pf.u[2] = h ? keep0 : r0;
    pf.u[3] = h ? keep1 : r1;
    __builtin_amdgcn_s_setprio(1);
    o0 = __builtin_amdgcn_mfma_f32_32x32x16_bf16(vf[c][0], pf.v, o0, 0, 0, 0);
    o1 = __builtin_amdgcn_mfma_f32_32x32x16_bf16(vf[c][1], pf.v, o1, 0, 0, 0);
    __builtin_amdgcn_s_setprio(0);
  }
}

__global__ __launch_bounds__(256, 2) void attn_kernel(const bf16* __restrict__ qkv,
    const bf16* __restrict__ vt, bf16* __restrict__ outb)
{
  __shared__ float Osh[4][32][65];   // padded: conflict-free stash
  __shared__ float msh[4][32];
  __shared__ float lsh[4][32];

  const int tid = threadIdx.x;
  const int wv = tid >> 6;
  const int lane = tid & 63;
  const int q5 = lane & 31, h = lane >> 5;
  const int hh = blockIdx.x;        // head fastest -> head's K/V pinned per XCD L2
  const int q0 = blockIdx.y * 32;

  // Q fragment (B-operand rows), prescaled by 1/8 (exact in bf16)
  const bf16* qb = qkv + (size_t)(q0 + q5)*3072 + hh*64 + h*8;
  bf16x8 qf[4];
#pragma unroll
  for (int dc = 0; dc < 4; ++dc) {
    bf16x8 x = *(const bf16x8*)(qb + dc*16);
#pragma unroll
    for (int j = 0; j < 8; ++j) x[j] = (bf16)(0.125f * (float)x[j]);
    qf[dc] = x;
  }

  const bf16* kb = qkv + 1024 + hh*64 + h*8;
  const bf16* vb = vt + (size_t)hh*64*2048 + h*8;

  f32x16 o0, o1;
#pragma unroll
  for (int r = 0; r < 16; ++r) { o0[r] = 0.f; o1[r] = 0.f; }
  float m = -1e30f, lsum = 0.f;

  // prologue: K tile 0
  bf16x8 ka[4], ka2[4];
  {
    const bf16* kp = kb + (size_t)(wv*32 + q5)*3072;
#pragma unroll
    for (int dc = 0; dc < 4; ++dc) ka[dc] = *(const bf16x8*)(kp + dc*16);
  }

  // 16 tiles per wave, interleaved KV-split, ping-pong K buffers
  for (int t = 0; t < 16; t += 2) {
    attn_tile32(kb, vb, qf, ka, ka2, o0, o1, m, lsum,
                (wv + 4*t)*32,     ((wv + 4*(t+1)) & 63)*32, q5, h);
    attn_tile32(kb, vb, qf, ka2, ka, o0, o1, m, lsum,
                (wv + 4*(t+1))*32, ((wv + 4*(t+2)) & 63)*32, q5, h);
  }

  // stash wave partials: O'[d][q] -> Osh[wv][q][d]
#pragma unroll
  for (int r = 0; r < 16; ++r) {
    const int dr = (r & 3) + 8*(r >> 2) + 4*h;
    Osh[wv][q5][dr]      = o0[r];
    Osh[wv][q5][32 + dr] = o1[r];
  }
  if (h == 0) { msh[wv][q5] = m; lsh[wv][q5] = lsum; }
  __syncthreads();

  // merge 4 partials: thread -> (q = tid>>3, 8 d's at (tid&7)*8)
  const int q = tid >> 3, d0 = (tid & 7) * 8;
  float mm = fmaxf(fmaxf(msh[0][q], msh[1][q]), fmaxf(msh[2][q], msh[3][q]));
  float e0 = __expf(msh[0][q] - mm), e1 = __expf(msh[1][q] - mm),
        e2 = __expf(msh[2][q] - mm), e3 = __expf(msh[3][q] - mm);
  float L = e0*lsh[0][q] + e1*lsh[1][q] + e2*lsh[2][q] + e3*lsh[3][q];
  float rinv = 1.0f / L;
  bf16x8 outv;
#pragma unroll
  for (int j = 0; j < 8; ++j) {
    float sum = e0*Osh[0][q][d0+j] + e1*Osh[1][q][d0+j]
              + e2*Osh[2][q][d0+j] + e3*Osh[3][q][d0+j];
    outv[j] = (bf16)(sum * rinv);
  }
  *(bf16x8*)&outb[(size_t)(q0 + q)*DIM + hh*64 + d0] = outv;
}

// ---------------- small kernels ----------------
__global__ __launch_bounds__(256) void rope_init_kernel(float* __restrict__ ct, float* __restrict__ st) {
  int idx = blockIdx.x * 256 + threadIdx.x;
  if (idx >= SEQ * 32) return;
  int s = idx >> 5, i = idx & 31;
  float inv = powf(10000.0f, -(float)i / 32.0f);
  float f = (float)s * inv;
  ct[idx] = cosf(f);
  st[idx] = sinf(f);
}

__global__ __launch_bounds__(256) void cast_kernel(const float* __restrict__ src,
    bf16* __restrict__ dst, int perLayer, int dstStride, int dstOff, int L)
{
  int i = blockIdx.x * 256 + threadIdx.x;
  int e = i * 4;
  if (e >= perLayer * L) return;
  int l = e / perLayer;
  int o = e - l * perLayer;
  float4 v = *(const float4*)(src + e);
  bf16x4 b;
  b[0] = (bf16)v.x; b[1] = (bf16)v.y; b[2] = (bf16)v.z; b[3] = (bf16)v.w;
  *(bf16x4*)(dst + (size_t)l * dstStride + dstOff + o) = b;
}

__global__ __launch_bounds__(256) void embed_kernel(const int* __restrict__ tok,
    const float* __restrict__ emb, float* __restrict__ h)
{
  int s = blockIdx.x, t = threadIdx.x;
  int v = tok[s];
  ((float4*)(h + (size_t)s * DIM))[t] = ((const float4*)(emb + (size_t)v * DIM))[t];
}

__global__ __launch_bounds__(256) void rmsnorm_kernel(const float* __restrict__ h,
    const float* __restrict__ w, bf16* __restrict__ outb)
{
  int row = blockIdx.x, tid = threadIdx.x;
  float4 v = ((const float4*)(h + (size_t)row * DIM))[tid];
  float ss = v.x*v.x + v.y*v.y + v.z*v.z + v.w*v.w;
#pragma unroll
  for (int off = 1; off < 64; off <<= 1) ss += __shfl_xor(ss, off);
  __shared__ float red[4];
  if ((tid & 63) == 0) red[tid >> 6] = ss;
  __syncthreads();
  float tot = red[0] + red[1] + red[2] + red[3];
  float inv = rsqrtf(tot * (1.0f / DIM) + 1e-5f);
  float4 wv4 = ((const float4*)w)[tid];
  bf16x4 o;
  o[0] = (bf16)(v.x * inv * wv4.x);
  o[1] = (bf16)(v.y * inv * wv4.y);
  o[2] = (bf16)(v.z * inv * wv4.z);
  o[3] = (bf16)(v.w * inv * wv4.w);
  ((bf16x4*)(outb + (size_t)row * DIM))[tid] = o;
}

__global__ __launch_bounds__(256) void final_rms_kernel(const float* __restrict__ hrow,
    const float* __restrict__ w, float* __restrict__ fl)
{
  int tid = threadIdx.x;
  float4 v = ((const float4*)hrow)[tid];
  float ss = v.x*v.x + v.y*v.y + v.z*v.z + v.w*v.w;
#pragma unroll
  for (int off = 1; off < 64; off <<= 1) ss += __shfl_xor(ss, off);
  __shared__ float red[4];
  if ((tid & 63) == 0) red[tid >> 6] = ss;
  __syncthreads();
  float tot = red[0] + red[1] + red[2] + red[3];
  float inv = rsqrtf(tot * (1.0f / DIM) + 1e-5f);
  float4 wv4 = ((const float4*)w)[tid];
  float4 o;
  o.x = v.x * inv * wv4.x;
  o.y = v.y * inv * wv4.y;
  o.z = v.z * inv * wv4.z;
  o.w = v.w * inv * wv4.w;
  ((float4*)fl)[tid] = o;
}

// RoPE over q,k: each thread handles 8 contiguous bf16 (4 rot pairs) in one head.
__global__ __launch_bounds__(256) void rope_kernel(bf16* __restrict__ qkv,
    const float* __restrict__ ct, const float* __restrict__ st)
{
  int idx = blockIdx.x * 256 + threadIdx.x;
  if (idx >= SEQ * 128) return;
  int s = idx >> 7, rem = idx & 127;
  int h = rem >> 3, c8 = rem & 7;
  int d0 = c8 * 8, i0 = c8 * 4;
  float4 cv = *(const float4*)&ct[s*32 + i0];
  float4 sv = *(const float4*)&st[s*32 + i0];
  float c[4]  = {cv.x, cv.y, cv.z, cv.w};
  float sn[4] = {sv.x, sv.y, sv.z, sv.w};
  size_t base = (size_t)s * 3072 + h * 64 + d0;
#pragma unroll
  for (int part = 0; part < 2; ++part) {
    bf16x8 x = *(bf16x8*)&qkv[base + part * 1024];
    bf16x8 o;
#pragma unroll
    for (int p = 0; p < 4; ++p) {
      float xr = (float)x[2*p], xi = (float)x[2*p+1];
      o[2*p]   = (bf16)(xr * c[p] - xi * sn[p]);
      o[2*p+1] = (bf16)(xr * sn[p] + xi * c[p]);
    }
    *(bf16x8*)&qkv[base + part * 1024] = o;
  }
}

__global__ __launch_bounds__(256) void vtrans_kernel(const bf16* __restrict__ qkv,
    bf16* __restrict__ vt)
{
  int i = blockIdx.x * 256 + threadIdx.x;
  if (i >= SEQ * DIM) return;
  int d = i >> 11, j = i & 2047;
  vt[(size_t)d * SEQ + j] = qkv[(size_t)j * 3072 + 2048 + d];
}

__global__ __launch_bounds__(256) void silu_kernel(const bf16* __restrict__ ug,
    bf16* __restrict__ hb)
{
  int i = blockIdx.x * 256 + threadIdx.x;
  int s = i / 352, j8 = (i - s * 352) * 8;
  if (s >= SEQ) return;
  bf16x8 u = *(const bf16x8*)&ug[(size_t)s * 5632 + j8];
  bf16x8 g = *(const bf16x8*)&ug[(size_t)s * 5632 + 2816 + j8];
  bf16x8 o;
#pragma unroll
  for (int t = 0; t < 8; ++t) {
    float x = (float)u[t];
    float y = x / (1.f + __expf(-x)) * (float)g[t];
    o[t] = (bf16)y;
  }
  *(bf16x8*)&hb[(size_t)s * HID + j8] = o;
}

__global__ __launch_bounds__(64) void logits_kernel(const float* __restrict__ fl,
    const float* __restrict__ ow, float* __restrict__ outp)
{
  int v = blockIdx.x, lane = threadIdx.x;
  const float* row = ow + (size_t)v * DIM;
  float s = 0.f;
#pragma unroll
  for (int t = 0; t < 16; ++t) {
    int d = t * 64 + lane;
    s += fl[d] * row[d];
  }
#pragma unroll
  for (int off = 1; off < 64; off <<= 1) s += __shfl_xor(s, off);
  if (lane == 0) outp[v] = s;
}

// ---------------- host ----------------
extern "C" void kernel_launch(void* const* d_in, const int* in_sizes, int n_in,
                              void* d_out, int out_size, void* d_ws, size_t ws_size,
                              hipStream_t stream)
{
  const int*   tokens = (const int*)  d_in[0];
  const float* temb   = (const float*)d_in[1];
  const float* wq  = (const float*)d_in[2];
  const float* wk  = (const float*)d_in[3];
  const float* wvv = (const float*)d_in[4];
  const float* wo  = (const float*)d_in[5];
  const float* w1  = (const float*)d_in[6];
  const float* w2  = (const float*)d_in[7];
  const float* w3  = (const float*)d_in[8];
  const float* anw = (const float*)d_in[9];
  const float* fnw = (const float*)d_in[10];
  const float* finw= (const float*)d_in[11];
  const float* outw= (const float*)d_in[12];
  float* out = (float*)d_out;

  char* wsp = (char*)d_ws;
  size_t off = 0;
  auto take = [&](size_t bytes) -> void* {
    void* r = wsp + off;
    off += (bytes + 255) & ~(size_t)255;
    return r;
  };
  bf16* wqkv = (bf16*)take((size_t)NLAYER * 3072 * DIM * 2);
  bf16* wob  = (bf16*)take((size_t)NLAYER * DIM * DIM * 2);
  bf16* w13  = (bf16*)take((size_t)NLAYER * 2 * HID * DIM * 2);
  bf16* w2b  = (bf16*)take((size_t)NLAYER * DIM * HID * 2);
  float* h   = (float*)take((size_t)SEQ * DIM * 4);
  bf16* xn   = (bf16*)take((size_t)SEQ * DIM * 2);
  bf16* qkvb = (bf16*)take((size_t)SEQ * 3072 * 2);
  bf16* vtb  = (bf16*)take((size_t)DIM * SEQ * 2);
  bf16* attnb= (bf16*)take((size_t)SEQ * DIM * 2);
  bf16* ugb  = (bf16*)take((size_t)SEQ * 2 * HID * 2);
  bf16* hbb  = (bf16*)take((size_t)SEQ * HID * 2);
  float* ct  = (float*)take((size_t)SEQ * 32 * 4);
  float* st  = (float*)take((size_t)SEQ * 32 * 4);
  float* fl  = (float*)take((size_t)DIM * 4);

  rope_init_kernel<<<SEQ * 32 / 256, 256, 0, stream>>>(ct, st);

  const int PLd = DIM * DIM;        // 1048576
  const int PLh = HID * DIM;        // 2883584
  cast_kernel<<<PLd * NLAYER / 1024, 256, 0, stream>>>(wq,  wqkv, PLd, 3 * PLd, 0,       NLAYER);
  cast_kernel<<<PLd * NLAYER / 1024, 256, 0, stream>>>(wk,  wqkv, PLd, 3 * PLd, PLd,     NLAYER);
  cast_kernel<<<PLd * NLAYER / 1024, 256, 0, stream>>>(wvv, wqkv, PLd, 3 * PLd, 2 * PLd, NLAYER);
  cast_kernel<<<PLd * NLAYER / 1024, 256, 0, stream>>>(wo,  wob,  PLd, PLd,     0,       NLAYER);
  cast_kernel<<<PLh * NLAYER / 1024, 256, 0, stream>>>(w1,  w13,  PLh, 2 * PLh, 0,       NLAYER);
  cast_kernel<<<PLh * NLAYER / 1024, 256, 0, stream>>>(w3,  w13,  PLh, 2 * PLh, PLh,     NLAYER);
  cast_kernel<<<PLh * NLAYER / 1024, 256, 0, stream>>>(w2,  w2b,  PLh, PLh,     0,       NLAYER);

  embed_kernel<<<SEQ, 256, 0, stream>>>(tokens, temb, h);

  for (int l = 0; l < NLAYER; ++l) {
    const bf16* lwqkv = wqkv + (size_t)l * 3 * PLd;
    const bf16* lwo   = wob  + (size_t)l * PLd;
    const bf16* lw13  = w13  + (size_t)l * 2 * PLh;
    const bf16* lw2   = w2b  + (size_t)l * PLh;

    rmsnorm_kernel<<<SEQ, 256, 0, stream>>>(h, anw + l * DIM, xn);
    gemm_bt<0,128,128><<<dim3(24, 16), 256, 0, stream>>>(xn, lwqkv, qkvb, nullptr, nullptr, SEQ, 3072, DIM);
    rope_kernel<<<SEQ * 128 / 256, 256, 0, stream>>>(qkvb, ct, st);
    vtrans_kernel<<<SEQ * DIM / 256, 256, 0, stream>>>(qkvb, vtb);
    attn_kernel<<<dim3(16, 64), 256, 0, stream>>>(qkvb, vtb, attnb);
    gemm_bt<1,64,64><<<dim3(16, 32), 256, 0, stream>>>(attnb, lwo, nullptr, h, h, SEQ, DIM, DIM);
    rmsnorm_kernel<<<SEQ, 256, 0, stream>>>(h, fnw + l * DIM, xn);
    gemm_bt<0,128,128><<<dim3(44, 16), 256, 0, stream>>>(xn, lw13, ugb, nullptr, nullptr, SEQ, 2 * HID, DIM);
    silu_kernel<<<SEQ * HID / 8 / 256, 256, 0, stream>>>(ugb, hbb);
    gemm_bt<1,64,64><<<dim3(16, 32), 256, 0, stream>>>(hbb, lw2, nullptr, h, h, SEQ, DIM, HID);
  }

  final_rms_kernel<<<1, 256, 0, stream>>>(h + (size_t)(SEQ - 1) * DIM, finw, fl);
  logits_kernel<<<256, 64, 0, stream>>>(fl, outw, out);
}

// Round 8
// 793.219 us; speedup vs baseline: 1.7686x; 1.1230x over previous
//
#include <hip/hip_runtime.h>
#include <stdint.h>

typedef __bf16 bf16;
typedef __bf16 bf16x4 __attribute__((ext_vector_type(4)));
typedef __bf16 bf16x8 __attribute__((ext_vector_type(8)));
typedef float f32x4 __attribute__((ext_vector_type(4)));
typedef float f32x16 __attribute__((ext_vector_type(16)));

#define SEQ 2048
#define DIM 1024
#define NHEAD 16
#define HDIM 64
#define HID 2816
#define NLAYER 4

__device__ __forceinline__ void gload_lds16(const void* g, void* l) {
  __builtin_amdgcn_global_load_lds(
      (const __attribute__((address_space(1))) void*)g,
      (__attribute__((address_space(3))) void*)l, 16, 0, 0);
}

// ---------------- GEMM: C[M,N] = A[M,K] @ B[N,K]^T ----------------
// 2-phase double-buffered staging: stage tile k+1 while MFMA'ing tile k.
// MODE 0: Cb[idx] = (bf16)acc.  MODE 1: Cf[idx] = R[idx] + acc (f32 residual).
template <int MODE, int BM, int BN>
__global__ __launch_bounds__(256) void gemm_bt(
    const bf16* __restrict__ A, const bf16* __restrict__ B,
    bf16* __restrict__ Cb, float* __restrict__ Cf, const float* R,
    int M, int N, int K)
{
  constexpr int MR = BM / 32;       // per-wave m-fragments (16-row)
  constexpr int NR = BN / 32;       // per-wave n-fragments
  constexpr int LA = BM / 64;       // gloads per thread for A (1 or 2)
  constexpr int LB = BN / 64;
  __shared__ bf16 As[2 * BM * 32];
  __shared__ bf16 Bs[2 * BN * 32];
  const int tid  = threadIdx.x;
  const int wv   = tid >> 6;
  const int lane = tid & 63;
  const int lo = lane & 15, hi = lane >> 4;
  const int row0 = blockIdx.y * BM;
  const int col0 = blockIdx.x * BN;
  const int wr = (wv >> 1) * (BM / 2);
  const int wc = (wv & 1) * (BN / 2);

  f32x4 acc[MR][NR];
  const f32x4 zero = {0.f, 0.f, 0.f, 0.f};
#pragma unroll
  for (int m = 0; m < MR; ++m)
#pragma unroll
    for (int n = 0; n < NR; ++n) acc[m][n] = zero;

  const bf16* ag = A + (size_t)(row0 + (tid >> 2)) * K + (tid & 3) * 8;
  const bf16* bg = B + (size_t)(col0 + (tid >> 2)) * K + (tid & 3) * 8;

  auto stage = [&](int buf, int k) {
#pragma unroll
    for (int i = 0; i < LA; ++i)
      gload_lds16(ag + k + (size_t)i*64*K, &As[buf*BM*32 + i*2048 + wv*512]);
#pragma unroll
    for (int i = 0; i < LB; ++i)
      gload_lds16(bg + k + (size_t)i*64*K, &Bs[buf*BN*32 + i*2048 + wv*512]);
  };
  auto compute = [&](int buf) {
    bf16x8 af[MR], bfv[NR];
#pragma unroll
    for (int m = 0; m < MR; ++m)
      af[m] = *(const bf16x8*)&As[buf*BM*32 + (wr + m*16 + lo)*32 + hi*8];
#pragma unroll
    for (int n = 0; n < NR; ++n)
      bfv[n] = *(const bf16x8*)&Bs[buf*BN*32 + (wc + n*16 + lo)*32 + hi*8];
#pragma unroll
    for (int m = 0; m < MR; ++m)
#pragma unroll
      for (int n = 0; n < NR; ++n)
        acc[m][n] = __builtin_amdgcn_mfma_f32_16x16x32_bf16(af[m], bfv[n], acc[m][n], 0, 0, 0);
  };

  // prologue
  stage(0, 0);
  __syncthreads();
  // main loop: 2 K-steps (64 cols) per iteration, static ping-pong buffers.
  // K is a multiple of 64 for all call sites (1024, 2816).
  for (int k0 = 0; k0 < K; k0 += 64) {
    stage(1, k0 + 32);                 // overlap with compute(0)
    compute(0);
    __syncthreads();                   // drains stage(1) vmcnt + ds reads
    if (k0 + 64 < K) stage(0, k0 + 64);
    compute(1);
    __syncthreads();
  }

#pragma unroll
  for (int m = 0; m < MR; ++m)
#pragma unroll
    for (int n = 0; n < NR; ++n)
#pragma unroll
      for (int r = 0; r < 4; ++r) {
        const int row = row0 + wr + m * 16 + hi * 4 + r;
        const int col = col0 + wc + n * 16 + lo;
        const size_t idx = (size_t)row * N + col;
        if (MODE == 0) Cb[idx] = (bf16)acc[m][n][r];
        else           Cf[idx] = R[idx] + acc[m][n][r];
      }
}

// ---------------- flash attention: swapped QK^T on 32x32x16 MFMA ----------------
// QBLK=64: TWO q-tiles per wave share every K and V fragment. 4-wave KV-split,
// KVBLK=32. Lane (q5=lane&31, h=lane>>5).
// QK^T: S' = mfma(K,Q) -> lane holds S[k=crow(r,h)][q=q5], crow=(r&3)+8*(r>>2)+4*h.
// Softmax lane-local. P packed to bf16 in-register; PV B-frag built by
// exchanging the partner k-quad across lane-halves. PV: O' = mfma(V^T, P).
__device__ __forceinline__ void softmax_pv(
    f32x16& s, float& m, float& lsum, f32x16& o0, f32x16& o1,
    const bf16x8 (&vf)[2][2], int h)
{
  // row max over k (16 in-lane + cross-half)
  float mx = s[0];
#pragma unroll
  for (int r = 1; r < 16; ++r) mx = fmaxf(mx, s[r]);
  mx = fmaxf(mx, __shfl_xor(mx, 32));
  if (!__all(mx <= m + 8.0f)) {           // defer-max (THR=8)
    float mnew = fmaxf(m, mx);
    float corr = __expf(m - mnew);
    m = mnew; lsum *= corr;
#pragma unroll
    for (int r = 0; r < 16; ++r) { o0[r] *= corr; o1[r] *= corr; }
  }
  float p[16]; float ps = 0.f;
#pragma unroll
  for (int r = 0; r < 16; ++r) { p[r] = __expf(s[r] - m); ps += p[r]; }
  ps += __shfl_xor(ps, 32);
  lsum += ps;

  // pack P quads: w[g][t] holds k = 8g + 4h + {2t, 2t+1}
  unsigned int w[4][2];
#pragma unroll
  for (int g = 0; g < 4; ++g)
#pragma unroll
    for (int t2 = 0; t2 < 2; ++t2) {
      union { bf16 b[2]; unsigned int u; } pk;
      pk.b[0] = (bf16)p[g*4 + 2*t2];
      pk.b[1] = (bf16)p[g*4 + 2*t2 + 1];
      w[g][t2] = pk.u;
    }

  // per 16-k chunk: assemble B-frag P[q][k=c*16+h*8+j] (own quad + partner quad)
#pragma unroll
  for (int c = 0; c < 2; ++c) {
    unsigned int keep0 = h ? w[2*c+1][0] : w[2*c][0];
    unsigned int keep1 = h ? w[2*c+1][1] : w[2*c][1];
    unsigned int send0 = h ? w[2*c][0]   : w[2*c+1][0];
    unsigned int send1 = h ? w[2*c][1]   : w[2*c+1][1];
    unsigned int r0 = __shfl_xor(send0, 32);
    unsigned int r1 = __shfl_xor(send1, 32);
    union { unsigned int u[4]; bf16x8 v; } pf;
    pf.u[0] = h ? r0 : keep0;
    pf.u[1] = h ? r1 : keep1;
    pf.u[2] = h ? keep0 : r0;
    pf.u[3] = h ? keep1 : r1;
    __builtin_amdgcn_s_setprio(1);
    o0 = __builtin_amdgcn_mfma_f32_32x32x16_bf16(vf[c][0], pf.v, o0, 0, 0, 0);
    o1 = __builtin_amdgcn_mfma_f32_32x32x16_bf16(vf[c][1], pf.v, o1, 0, 0, 0);
    __builtin_amdgcn_s_setprio(0);
  }
}

__device__ __forceinline__ void attn_tile64(
    const bf16* __restrict__ kb, const bf16* __restrict__ vb,
    const bf16x8 (&qfA)[4], const bf16x8 (&qfB)[4],
    bf16x8 (&kc)[4], bf16x8 (&kn)[4],
    f32x16& oA0, f32x16& oA1, f32x16& oB0, f32x16& oB1,
    float& mA, float& lA, float& mB, float& lB,
    int j0, int jn, int q5, int h)
{
  // V for current tile: issued now, consumed after softmax (latency cover)
  bf16x8 vf[2][2];
#pragma unroll
  for (int c = 0; c < 2; ++c)
#pragma unroll
    for (int dh = 0; dh < 2; ++dh)
      vf[c][dh] = *(const bf16x8*)&vb[(size_t)(dh*32 + q5)*2048 + j0 + c*16];
  // next-tile K prefetch
  {
    const bf16* kp = kb + (size_t)(jn + q5)*3072;
#pragma unroll
    for (int dc = 0; dc < 4; ++dc) kn[dc] = *(const bf16x8*)(kp + dc*16);
  }
  // QK^T for both q-tiles over the SAME K fragments (two independent chains)
  f32x16 sA, sB;
#pragma unroll
  for (int r = 0; r < 16; ++r) { sA[r] = 0.f; sB[r] = 0.f; }
  __builtin_amdgcn_s_setprio(1);
#pragma unroll
  for (int dc = 0; dc < 4; ++dc) {
    sA = __builtin_amdgcn_mfma_f32_32x32x16_bf16(kc[dc], qfA[dc], sA, 0, 0, 0);
    sB = __builtin_amdgcn_mfma_f32_32x32x16_bf16(kc[dc], qfB[dc], sB, 0, 0, 0);
  }
  __builtin_amdgcn_s_setprio(0);

  softmax_pv(sA, mA, lA, oA0, oA1, vf, h);
  softmax_pv(sB, mB, lB, oB0, oB1, vf, h);
}

__global__ __launch_bounds__(256, 2) void attn_kernel(const bf16* __restrict__ qkv,
    const bf16* __restrict__ vt, bf16* __restrict__ outb)
{
  __shared__ float Osh[4][32][65];   // padded merge stash (reused for both q-tiles)
  __shared__ float msh[4][32];
  __shared__ float lsh[4][32];

  const int tid = threadIdx.x;
  const int wv = tid >> 6;
  const int lane = tid & 63;
  const int q5 = lane & 31, h = lane >> 5;
  const int hh = blockIdx.x;        // head fastest -> head's K/V pinned per XCD L2
  const int q0 = blockIdx.y * 64;

  // Q fragments for both q-tiles (B-operand rows), prescaled by 1/8
  bf16x8 qfA[4], qfB[4];
#pragma unroll
  for (int dc = 0; dc < 4; ++dc) {
    bf16x8 xa = *(const bf16x8*)&qkv[(size_t)(q0 + q5)*3072      + hh*64 + h*8 + dc*16];
    bf16x8 xb = *(const bf16x8*)&qkv[(size_t)(q0 + 32 + q5)*3072 + hh*64 + h*8 + dc*16];
#pragma unroll
    for (int j = 0; j < 8; ++j) {
      xa[j] = (bf16)(0.125f * (float)xa[j]);
      xb[j] = (bf16)(0.125f * (float)xb[j]);
    }
    qfA[dc] = xa; qfB[dc] = xb;
  }

  const bf16* kb = qkv + 1024 + hh*64 + h*8;
  const bf16* vb = vt + (size_t)hh*64*2048 + h*8;

  f32x16 oA0, oA1, oB0, oB1;
#pragma unroll
  for (int r = 0; r < 16; ++r) { oA0[r]=0.f; oA1[r]=0.f; oB0[r]=0.f; oB1[r]=0.f; }
  float mA = -1e30f, lA = 0.f, mB = -1e30f, lB = 0.f;

  // prologue: K tile 0
  bf16x8 ka[4], ka2[4];
  {
    const bf16* kp = kb + (size_t)(wv*32 + q5)*3072;
#pragma unroll
    for (int dc = 0; dc < 4; ++dc) ka[dc] = *(const bf16x8*)(kp + dc*16);
  }

  // 16 tiles per wave, interleaved KV-split, ping-pong K buffers
  for (int t = 0; t < 16; t += 2) {
    attn_tile64(kb, vb, qfA, qfB, ka, ka2, oA0, oA1, oB0, oB1,
                mA, lA, mB, lB,
                (wv + 4*t)*32,     ((wv + 4*(t+1)) & 63)*32, q5, h);
    attn_tile64(kb, vb, qfA, qfB, ka2, ka, oA0, oA1, oB0, oB1,
                mA, lA, mB, lB,
                (wv + 4*(t+1))*32, ((wv + 4*(t+2)) & 63)*32, q5, h);
  }

  // ---- merge pass A (rows q0..q0+31), then pass B (rows q0+32..q0+63) ----
  const int q = tid >> 3, d0 = (tid & 7) * 8;
#pragma unroll
  for (int pass = 0; pass < 2; ++pass) {
    const f32x16& p0 = pass ? oB0 : oA0;
    const f32x16& p1 = pass ? oB1 : oA1;
#pragma unroll
    for (int r = 0; r < 16; ++r) {
      const int dr = (r & 3) + 8*(r >> 2) + 4*h;
      Osh[wv][q5][dr]      = p0[r];
      Osh[wv][q5][32 + dr] = p1[r];
    }
    if (h == 0) {
      msh[wv][q5] = pass ? mB : mA;
      lsh[wv][q5] = pass ? lB : lA;
    }
    __syncthreads();
    {
      float mm = fmaxf(fmaxf(msh[0][q], msh[1][q]), fmaxf(msh[2][q], msh[3][q]));
      float e0 = __expf(msh[0][q] - mm), e1 = __expf(msh[1][q] - mm),
            e2 = __expf(msh[2][q] - mm), e3 = __expf(msh[3][q] - mm);
      float L = e0*lsh[0][q] + e1*lsh[1][q] + e2*lsh[2][q] + e3*lsh[3][q];
      float rinv = 1.0f / L;
      bf16x8 outv;
#pragma unroll
      for (int j = 0; j < 8; ++j) {
        float sum = e0*Osh[0][q][d0+j] + e1*Osh[1][q][d0+j]
                  + e2*Osh[2][q][d0+j] + e3*Osh[3][q][d0+j];
        outv[j] = (bf16)(sum * rinv);
      }
      *(bf16x8*)&outb[(size_t)(q0 + pass*32 + q)*DIM + hh*64 + d0] = outv;
    }
    __syncthreads();   // Osh/msh/lsh reused by next pass
  }
}

// ---------------- small kernels ----------------
__global__ __launch_bounds__(256) void rope_init_kernel(float* __restrict__ ct, float* __restrict__ st) {
  int idx = blockIdx.x * 256 + threadIdx.x;
  if (idx >= SEQ * 32) return;
  int s = idx >> 5, i = idx & 31;
  float inv = powf(10000.0f, -(float)i / 32.0f);
  float f = (float)s * inv;
  ct[idx] = cosf(f);
  st[idx] = sinf(f);
}

__global__ __launch_bounds__(256) void cast_kernel(const float* __restrict__ src,
    bf16* __restrict__ dst, int perLayer, int dstStride, int dstOff, int L)
{
  int i = blockIdx.x * 256 + threadIdx.x;
  int e = i * 4;
  if (e >= perLayer * L) return;
  int l = e / perLayer;
  int o = e - l * perLayer;
  float4 v = *(const float4*)(src + e);
  bf16x4 b;
  b[0] = (bf16)v.x; b[1] = (bf16)v.y; b[2] = (bf16)v.z; b[3] = (bf16)v.w;
  *(bf16x4*)(dst + (size_t)l * dstStride + dstOff + o) = b;
}

__global__ __launch_bounds__(256) void embed_kernel(const int* __restrict__ tok,
    const float* __restrict__ emb, float* __restrict__ h)
{
  int s = blockIdx.x, t = threadIdx.x;
  int v = tok[s];
  ((float4*)(h + (size_t)s * DIM))[t] = ((const float4*)(emb + (size_t)v * DIM))[t];
}

__global__ __launch_bounds__(256) void rmsnorm_kernel(const float* __restrict__ h,
    const float* __restrict__ w, bf16* __restrict__ outb)
{
  int row = blockIdx.x, tid = threadIdx.x;
  float4 v = ((const float4*)(h + (size_t)row * DIM))[tid];
  float ss = v.x*v.x + v.y*v.y + v.z*v.z + v.w*v.w;
#pragma unroll
  for (int off = 1; off < 64; off <<= 1) ss += __shfl_xor(ss, off);
  __shared__ float red[4];
  if ((tid & 63) == 0) red[tid >> 6] = ss;
  __syncthreads();
  float tot = red[0] + red[1] + red[2] + red[3];
  float inv = rsqrtf(tot * (1.0f / DIM) + 1e-5f);
  float4 wv4 = ((const float4*)w)[tid];
  bf16x4 o;
  o[0] = (bf16)(v.x * inv * wv4.x);
  o[1] = (bf16)(v.y * inv * wv4.y);
  o[2] = (bf16)(v.z * inv * wv4.z);
  o[3] = (bf16)(v.w * inv * wv4.w);
  ((bf16x4*)(outb + (size_t)row * DIM))[tid] = o;
}

__global__ __launch_bounds__(256) void final_rms_kernel(const float* __restrict__ hrow,
    const float* __restrict__ w, float* __restrict__ fl)
{
  int tid = threadIdx.x;
  float4 v = ((const float4*)hrow)[tid];
  float ss = v.x*v.x + v.y*v.y + v.z*v.z + v.w*v.w;
#pragma unroll
  for (int off = 1; off < 64; off <<= 1) ss += __shfl_xor(ss, off);
  __shared__ float red[4];
  if ((tid & 63) == 0) red[tid >> 6] = ss;
  __syncthreads();
  float tot = red[0] + red[1] + red[2] + red[3];
  float inv = rsqrtf(tot * (1.0f / DIM) + 1e-5f);
  float4 wv4 = ((const float4*)w)[tid];
  float4 o;
  o.x = v.x * inv * wv4.x;
  o.y = v.y * inv * wv4.y;
  o.z = v.z * inv * wv4.z;
  o.w = v.w * inv * wv4.w;
  ((float4*)fl)[tid] = o;
}

// RoPE over q,k: each thread handles 8 contiguous bf16 (4 rot pairs) in one head.
__global__ __launch_bounds__(256) void rope_kernel(bf16* __restrict__ qkv,
    const float* __restrict__ ct, const float* __restrict__ st)
{
  int idx = blockIdx.x * 256 + threadIdx.x;
  if (idx >= SEQ * 128) return;
  int s = idx >> 7, rem = idx & 127;
  int h = rem >> 3, c8 = rem & 7;
  int d0 = c8 * 8, i0 = c8 * 4;
  float4 cv = *(const float4*)&ct[s*32 + i0];
  float4 sv = *(const float4*)&st[s*32 + i0];
  float c[4]  = {cv.x, cv.y, cv.z, cv.w};
  float sn[4] = {sv.x, sv.y, sv.z, sv.w};
  size_t base = (size_t)s * 3072 + h * 64 + d0;
#pragma unroll
  for (int part = 0; part < 2; ++part) {
    bf16x8 x = *(bf16x8*)&qkv[base + part * 1024];
    bf16x8 o;
#pragma unroll
    for (int p = 0; p < 4; ++p) {
      float xr = (float)x[2*p], xi = (float)x[2*p+1];
      o[2*p]   = (bf16)(xr * c[p] - xi * sn[p]);
      o[2*p+1] = (bf16)(xr * sn[p] + xi * c[p]);
    }
    *(bf16x8*)&qkv[base + part * 1024] = o;
  }
}

__global__ __launch_bounds__(256) void vtrans_kernel(const bf16* __restrict__ qkv,
    bf16* __restrict__ vt)
{
  int i = blockIdx.x * 256 + threadIdx.x;
  if (i >= SEQ * DIM) return;
  int d = i >> 11, j = i & 2047;
  vt[(size_t)d * SEQ + j] = qkv[(size_t)j * 3072 + 2048 + d];
}

__global__ __launch_bounds__(256) void silu_kernel(const bf16* __restrict__ ug,
    bf16* __restrict__ hb)
{
  int i = blockIdx.x * 256 + threadIdx.x;
  int s = i / 352, j8 = (i - s * 352) * 8;
  if (s >= SEQ) return;
  bf16x8 u = *(const bf16x8*)&ug[(size_t)s * 5632 + j8];
  bf16x8 g = *(const bf16x8*)&ug[(size_t)s * 5632 + 2816 + j8];
  bf16x8 o;
#pragma unroll
  for (int t = 0; t < 8; ++t) {
    float x = (float)u[t];
    float y = x / (1.f + __expf(-x)) * (float)g[t];
    o[t] = (bf16)y;
  }
  *(bf16x8*)&hb[(size_t)s * HID + j8] = o;
}

__global__ __launch_bounds__(64) void logits_kernel(const float* __restrict__ fl,
    const float* __restrict__ ow, float* __restrict__ outp)
{
  int v = blockIdx.x, lane = threadIdx.x;
  const float* row = ow + (size_t)v * DIM;
  float s = 0.f;
#pragma unroll
  for (int t = 0; t < 16; ++t) {
    int d = t * 64 + lane;
    s += fl[d] * row[d];
  }
#pragma unroll
  for (int off = 1; off < 64; off <<= 1) s += __shfl_xor(s, off);
  if (lane == 0) outp[v] = s;
}

// ---------------- host ----------------
extern "C" void kernel_launch(void* const* d_in, const int* in_sizes, int n_in,
                              void* d_out, int out_size, void* d_ws, size_t ws_size,
                              hipStream_t stream)
{
  const int*   tokens = (const int*)  d_in[0];
  const float* temb   = (const float*)d_in[1];
  const float* wq  = (const float*)d_in[2];
  const float* wk  = (const float*)d_in[3];
  const float* wvv = (const float*)d_in[4];
  const float* wo  = (const float*)d_in[5];
  const float* w1  = (const float*)d_in[6];
  const float* w2  = (const float*)d_in[7];
  const float* w3  = (const float*)d_in[8];
  const float* anw = (const float*)d_in[9];
  const float* fnw = (const float*)d_in[10];
  const float* finw= (const float*)d_in[11];
  const float* outw= (const float*)d_in[12];
  float* out = (float*)d_out;

  char* wsp = (char*)d_ws;
  size_t off = 0;
  auto take = [&](size_t bytes) -> void* {
    void* r = wsp + off;
    off += (bytes + 255) & ~(size_t)255;
    return r;
  };
  bf16* wqkv = (bf16*)take((size_t)NLAYER * 3072 * DIM * 2);
  bf16* wob  = (bf16*)take((size_t)NLAYER * DIM * DIM * 2);
  bf16* w13  = (bf16*)take((size_t)NLAYER * 2 * HID * DIM * 2);
  bf16* w2b  = (bf16*)take((size_t)NLAYER * DIM * HID * 2);
  float* h   = (float*)take((size_t)SEQ * DIM * 4);
  bf16* xn   = (bf16*)take((size_t)SEQ * DIM * 2);
  bf16* qkvb = (bf16*)take((size_t)SEQ * 3072 * 2);
  bf16* vtb  = (bf16*)take((size_t)DIM * SEQ * 2);
  bf16* attnb= (bf16*)take((size_t)SEQ * DIM * 2);
  bf16* ugb  = (bf16*)take((size_t)SEQ * 2 * HID * 2);
  bf16* hbb  = (bf16*)take((size_t)SEQ * HID * 2);
  float* ct  = (float*)take((size_t)SEQ * 32 * 4);
  float* st  = (float*)take((size_t)SEQ * 32 * 4);
  float* fl  = (float*)take((size_t)DIM * 4);

  rope_init_kernel<<<SEQ * 32 / 256, 256, 0, stream>>>(ct, st);

  const int PLd = DIM * DIM;        // 1048576
  const int PLh = HID * DIM;        // 2883584
  cast_kernel<<<PLd * NLAYER / 1024, 256, 0, stream>>>(wq,  wqkv, PLd, 3 * PLd, 0,       NLAYER);
  cast_kernel<<<PLd * NLAYER / 1024, 256, 0, stream>>>(wk,  wqkv, PLd, 3 * PLd, PLd,     NLAYER);
  cast_kernel<<<PLd * NLAYER / 1024, 256, 0, stream>>>(wvv, wqkv, PLd, 3 * PLd, 2 * PLd, NLAYER);
  cast_kernel<<<PLd * NLAYER / 1024, 256, 0, stream>>>(wo,  wob,  PLd, PLd,     0,       NLAYER);
  cast_kernel<<<PLh * NLAYER / 1024, 256, 0, stream>>>(w1,  w13,  PLh, 2 * PLh, 0,       NLAYER);
  cast_kernel<<<PLh * NLAYER / 1024, 256, 0, stream>>>(w3,  w13,  PLh, 2 * PLh, PLh,     NLAYER);
  cast_kernel<<<PLh * NLAYER / 1024, 256, 0, stream>>>(w2,  w2b,  PLh, PLh,     0,       NLAYER);

  embed_kernel<<<SEQ, 256, 0, stream>>>(tokens, temb, h);

  for (int l = 0; l < NLAYER; ++l) {
    const bf16* lwqkv = wqkv + (size_t)l * 3 * PLd;
    const bf16* lwo   = wob  + (size_t)l * PLd;
    const bf16* lw13  = w13  + (size_t)l * 2 * PLh;
    const bf16* lw2   = w2b  + (size_t)l * PLh;

    rmsnorm_kernel<<<SEQ, 256, 0, stream>>>(h, anw + l * DIM, xn);
    gemm_bt<0,128,128><<<dim3(24, 16), 256, 0, stream>>>(xn, lwqkv, qkvb, nullptr, nullptr, SEQ, 3072, DIM);
    rope_kernel<<<SEQ * 128 / 256, 256, 0, stream>>>(qkvb, ct, st);
    vtrans_kernel<<<SEQ * DIM / 256, 256, 0, stream>>>(qkvb, vtb);
    attn_kernel<<<dim3(16, 32), 256, 0, stream>>>(qkvb, vtb, attnb);
    gemm_bt<1,64,64><<<dim3(16, 32), 256, 0, stream>>>(attnb, lwo, nullptr, h, h, SEQ, DIM, DIM);
    rmsnorm_kernel<<<SEQ, 256, 0, stream>>>(h, fnw + l * DIM, xn);
    gemm_bt<0,128,128><<<dim3(44, 16), 256, 0, stream>>>(xn, lw13, ugb, nullptr, nullptr, SEQ, 2 * HID, DIM);
    silu_kernel<<<SEQ * HID / 8 / 256, 256, 0, stream>>>(ugb, hbb);
    gemm_bt<1,64,64><<<dim3(16, 32), 256, 0, stream>>>(hbb, lw2, nullptr, h, h, SEQ, DIM, HID);
  }

  final_rms_kernel<<<1, 256, 0, stream>>>(h + (size_t)(SEQ - 1) * DIM, finw, fl);
  logits_kernel<<<256, 64, 0, stream>>>(fl, outw, out);
}

// Round 9
// 730.929 us; speedup vs baseline: 1.9193x; 1.0852x over previous
//
#include <hip/hip_runtime.h>
#include <stdint.h>

typedef __bf16 bf16;
typedef __bf16 bf16x4 __attribute__((ext_vector_type(4)));
typedef __bf16 bf16x8 __attribute__((ext_vector_type(8)));
typedef float f32x4 __attribute__((ext_vector_type(4)));
typedef float f32x16 __attribute__((ext_vector_type(16)));

#define SEQ 2048
#define DIM 1024
#define NHEAD 16
#define HDIM 64
#define HID 2816
#define NLAYER 4

__device__ __forceinline__ void gload_lds16(const void* g, void* l) {
  __builtin_amdgcn_global_load_lds(
      (const __attribute__((address_space(1))) void*)g,
      (__attribute__((address_space(3))) void*)l, 16, 0, 0);
}

// ---------------- GEMM: C[M,N] = A[M,K] @ B[N,K]^T ----------------
// 2-phase double-buffered staging: stage tile k+1 while MFMA'ing tile k.
// MODE 0: Cb[idx] = (bf16)acc.
// MODE 1: Cf[idx] = R[idx] + acc (f32 residual).
// MODE 2: SwiGLU epilogue — B rows are W1/W3 interleaved 16-at-a-time, so
//         n-frag pairs (2p,2p+1) hold matching (u,g) cols; writes
//         Cb[row][(N/2) cols] = silu(u)*g directly (ugb+silu kernel fused away).
template <int MODE, int BM, int BN>
__global__ __launch_bounds__(256) void gemm_bt(
    const bf16* __restrict__ A, const bf16* __restrict__ B,
    bf16* __restrict__ Cb, float* __restrict__ Cf, const float* R,
    int M, int N, int K)
{
  constexpr int MR = BM / 32;       // per-wave m-fragments (16-row)
  constexpr int NR = BN / 32;       // per-wave n-fragments
  constexpr int LA = BM / 64;       // gloads per thread for A (1 or 2)
  constexpr int LB = BN / 64;
  __shared__ bf16 As[2 * BM * 32];
  __shared__ bf16 Bs[2 * BN * 32];
  const int tid  = threadIdx.x;
  const int wv   = tid >> 6;
  const int lane = tid & 63;
  const int lo = lane & 15, hi = lane >> 4;
  const int row0 = blockIdx.y * BM;
  const int col0 = blockIdx.x * BN;
  const int wr = (wv >> 1) * (BM / 2);
  const int wc = (wv & 1) * (BN / 2);

  f32x4 acc[MR][NR];
  const f32x4 zero = {0.f, 0.f, 0.f, 0.f};
#pragma unroll
  for (int m = 0; m < MR; ++m)
#pragma unroll
    for (int n = 0; n < NR; ++n) acc[m][n] = zero;

  const bf16* ag = A + (size_t)(row0 + (tid >> 2)) * K + (tid & 3) * 8;
  const bf16* bg = B + (size_t)(col0 + (tid >> 2)) * K + (tid & 3) * 8;

  auto stage = [&](int buf, int k) {
#pragma unroll
    for (int i = 0; i < LA; ++i)
      gload_lds16(ag + k + (size_t)i*64*K, &As[buf*BM*32 + i*2048 + wv*512]);
#pragma unroll
    for (int i = 0; i < LB; ++i)
      gload_lds16(bg + k + (size_t)i*64*K, &Bs[buf*BN*32 + i*2048 + wv*512]);
  };
  auto compute = [&](int buf) {
    bf16x8 af[MR], bfv[NR];
#pragma unroll
    for (int m = 0; m < MR; ++m)
      af[m] = *(const bf16x8*)&As[buf*BM*32 + (wr + m*16 + lo)*32 + hi*8];
#pragma unroll
    for (int n = 0; n < NR; ++n)
      bfv[n] = *(const bf16x8*)&Bs[buf*BN*32 + (wc + n*16 + lo)*32 + hi*8];
#pragma unroll
    for (int m = 0; m < MR; ++m)
#pragma unroll
      for (int n = 0; n < NR; ++n)
        acc[m][n] = __builtin_amdgcn_mfma_f32_16x16x32_bf16(af[m], bfv[n], acc[m][n], 0, 0, 0);
  };

  // prologue
  stage(0, 0);
  __syncthreads();
  // main loop: 2 K-steps (64 cols) per iteration, static ping-pong buffers.
  // K is a multiple of 64 for all call sites (1024, 2816).
  for (int k0 = 0; k0 < K; k0 += 64) {
    stage(1, k0 + 32);                 // overlap with compute(0)
    compute(0);
    __syncthreads();                   // drains stage(1) vmcnt + ds reads
    if (k0 + 64 < K) stage(0, k0 + 64);
    compute(1);
    __syncthreads();
  }

  if (MODE == 2) {
    const int hstride = N >> 1;
#pragma unroll
    for (int m = 0; m < MR; ++m)
#pragma unroll
      for (int p = 0; p < NR/2; ++p)
#pragma unroll
        for (int r = 0; r < 4; ++r) {
          const int row  = row0 + wr + m * 16 + hi * 4 + r;
          const int hcol = (col0 + wc)/2 + p * 16 + lo;
          float u = acc[m][2*p][r], g = acc[m][2*p+1][r];
          float y = u / (1.f + __expf(-u)) * g;
          Cb[(size_t)row * hstride + hcol] = (bf16)y;
        }
  } else {
#pragma unroll
    for (int m = 0; m < MR; ++m)
#pragma unroll
      for (int n = 0; n < NR; ++n)
#pragma unroll
        for (int r = 0; r < 4; ++r) {
          const int row = row0 + wr + m * 16 + hi * 4 + r;
          const int col = col0 + wc + n * 16 + lo;
          const size_t idx = (size_t)row * N + col;
          if (MODE == 0) Cb[idx] = (bf16)acc[m][n][r];
          else           Cf[idx] = R[idx] + acc[m][n][r];
        }
  }
}

// ---------------- flash attention: swapped QK^T on 32x32x16 MFMA ----------------
// QBLK=64: TWO q-tiles per wave share every K and V fragment. 4-wave KV-split,
// KVBLK=32. Lane (q5=lane&31, h=lane>>5).
// QK^T: S' = mfma(K,Q) -> lane holds S[k=crow(r,h)][q=q5], crow=(r&3)+8*(r>>2)+4*h.
// Softmax lane-local. P packed to bf16 in-register; PV B-frag built by
// exchanging the partner k-quad across lane-halves. PV: O' = mfma(V^T, P).
__device__ __forceinline__ void softmax_pv(
    f32x16& s, float& m, float& lsum, f32x16& o0, f32x16& o1,
    const bf16x8 (&vf)[2][2], int h)
{
  // row max over k (16 in-lane + cross-half)
  float mx = s[0];
#pragma unroll
  for (int r = 1; r < 16; ++r) mx = fmaxf(mx, s[r]);
  mx = fmaxf(mx, __shfl_xor(mx, 32));
  if (!__all(mx <= m + 8.0f)) {           // defer-max (THR=8)
    float mnew = fmaxf(m, mx);
    float corr = __expf(m - mnew);
    m = mnew; lsum *= corr;
#pragma unroll
    for (int r = 0; r < 16; ++r) { o0[r] *= corr; o1[r] *= corr; }
  }
  float p[16]; float ps = 0.f;
#pragma unroll
  for (int r = 0; r < 16; ++r) { p[r] = __expf(s[r] - m); ps += p[r]; }
  ps += __shfl_xor(ps, 32);
  lsum += ps;

  // pack P quads: w[g][t] holds k = 8g + 4h + {2t, 2t+1}
  unsigned int w[4][2];
#pragma unroll
  for (int g = 0; g < 4; ++g)
#pragma unroll
    for (int t2 = 0; t2 < 2; ++t2) {
      union { bf16 b[2]; unsigned int u; } pk;
      pk.b[0] = (bf16)p[g*4 + 2*t2];
      pk.b[1] = (bf16)p[g*4 + 2*t2 + 1];
      w[g][t2] = pk.u;
    }

  // per 16-k chunk: assemble B-frag P[q][k=c*16+h*8+j] (own quad + partner quad)
#pragma unroll
  for (int c = 0; c < 2; ++c) {
    unsigned int keep0 = h ? w[2*c+1][0] : w[2*c][0];
    unsigned int keep1 = h ? w[2*c+1][1] : w[2*c][1];
    unsigned int send0 = h ? w[2*c][0]   : w[2*c+1][0];
    unsigned int send1 = h ? w[2*c][1]   : w[2*c+1][1];
    unsigned int r0 = __shfl_xor(send0, 32);
    unsigned int r1 = __shfl_xor(send1, 32);
    union { unsigned int u[4]; bf16x8 v; } pf;
    pf.u[0] = h ? r0 : keep0;
    pf.u[1] = h ? r1 : keep1;
    pf.u[2] = h ? keep0 : r0;
    pf.u[3] = h ? keep1 : r1;
    __builtin_amdgcn_s_setprio(1);
    o0 = __builtin_amdgcn_mfma_f32_32x32x16_bf16(vf[c][0], pf.v, o0, 0, 0, 0);
    o1 = __builtin_amdgcn_mfma_f32_32x32x16_bf16(vf[c][1], pf.v, o1, 0, 0, 0);
    __builtin_amdgcn_s_setprio(0);
  }
}

__device__ __forceinline__ void attn_tile64(
    const bf16* __restrict__ kb, const bf16* __restrict__ vb,
    const bf16x8 (&qfA)[4], const bf16x8 (&qfB)[4],
    bf16x8 (&kc)[4], bf16x8 (&kn)[4],
    f32x16& oA0, f32x16& oA1, f32x16& oB0, f32x16& oB1,
    float& mA, float& lA, float& mB, float& lB,
    int j0, int jn, int q5, int h)
{
  // V for current tile: issued now, consumed after softmax (latency cover)
  bf16x8 vf[2][2];
#pragma unroll
  for (int c = 0; c < 2; ++c)
#pragma unroll
    for (int dh = 0; dh < 2; ++dh)
      vf[c][dh] = *(const bf16x8*)&vb[(size_t)(dh*32 + q5)*2048 + j0 + c*16];
  // next-tile K prefetch
  {
    const bf16* kp = kb + (size_t)(jn + q5)*3072;
#pragma unroll
    for (int dc = 0; dc < 4; ++dc) kn[dc] = *(const bf16x8*)(kp + dc*16);
  }
  // QK^T for both q-tiles over the SAME K fragments (two independent chains)
  f32x16 sA, sB;
#pragma unroll
  for (int r = 0; r < 16; ++r) { sA[r] = 0.f; sB[r] = 0.f; }
  __builtin_amdgcn_s_setprio(1);
#pragma unroll
  for (int dc = 0; dc < 4; ++dc) {
    sA = __builtin_amdgcn_mfma_f32_32x32x16_bf16(kc[dc], qfA[dc], sA, 0, 0, 0);
    sB = __builtin_amdgcn_mfma_f32_32x32x16_bf16(kc[dc], qfB[dc], sB, 0, 0, 0);
  }
  __builtin_amdgcn_s_setprio(0);

  softmax_pv(sA, mA, lA, oA0, oA1, vf, h);
  softmax_pv(sB, mB, lB, oB0, oB1, vf, h);
}

__global__ __launch_bounds__(256, 2) void attn_kernel(const bf16* __restrict__ qkv,
    const bf16* __restrict__ vt, bf16* __restrict__ outb)
{
  __shared__ float Osh[4][32][65];   // padded merge stash (reused for both q-tiles)
  __shared__ float msh[4][32];
  __shared__ float lsh[4][32];

  const int tid = threadIdx.x;
  const int wv = tid >> 6;
  const int lane = tid & 63;
  const int q5 = lane & 31, h = lane >> 5;
  const int hh = blockIdx.x;        // head fastest -> head's K/V pinned per XCD L2
  const int q0 = blockIdx.y * 64;

  // Q fragments for both q-tiles (B-operand rows), prescaled by 1/8
  bf16x8 qfA[4], qfB[4];
#pragma unroll
  for (int dc = 0; dc < 4; ++dc) {
    bf16x8 xa = *(const bf16x8*)&qkv[(size_t)(q0 + q5)*3072      + hh*64 + h*8 + dc*16];
    bf16x8 xb = *(const bf16x8*)&qkv[(size_t)(q0 + 32 + q5)*3072 + hh*64 + h*8 + dc*16];
#pragma unroll
    for (int j = 0; j < 8; ++j) {
      xa[j] = (bf16)(0.125f * (float)xa[j]);
      xb[j] = (bf16)(0.125f * (float)xb[j]);
    }
    qfA[dc] = xa; qfB[dc] = xb;
  }

  const bf16* kb = qkv + 1024 + hh*64 + h*8;
  const bf16* vb = vt + (size_t)hh*64*2048 + h*8;

  f32x16 oA0, oA1, oB0, oB1;
#pragma unroll
  for (int r = 0; r < 16; ++r) { oA0[r]=0.f; oA1[r]=0.f; oB0[r]=0.f; oB1[r]=0.f; }
  float mA = -1e30f, lA = 0.f, mB = -1e30f, lB = 0.f;

  // prologue: K tile 0
  bf16x8 ka[4], ka2[4];
  {
    const bf16* kp = kb + (size_t)(wv*32 + q5)*3072;
#pragma unroll
    for (int dc = 0; dc < 4; ++dc) ka[dc] = *(const bf16x8*)(kp + dc*16);
  }

  // 16 tiles per wave, interleaved KV-split, ping-pong K buffers
  for (int t = 0; t < 16; t += 2) {
    attn_tile64(kb, vb, qfA, qfB, ka, ka2, oA0, oA1, oB0, oB1,
                mA, lA, mB, lB,
                (wv + 4*t)*32,     ((wv + 4*(t+1)) & 63)*32, q5, h);
    attn_tile64(kb, vb, qfA, qfB, ka2, ka, oA0, oA1, oB0, oB1,
                mA, lA, mB, lB,
                (wv + 4*(t+1))*32, ((wv + 4*(t+2)) & 63)*32, q5, h);
  }

  // ---- merge pass A (rows q0..q0+31), then pass B (rows q0+32..q0+63) ----
  const int q = tid >> 3, d0 = (tid & 7) * 8;
#pragma unroll
  for (int pass = 0; pass < 2; ++pass) {
    const f32x16& p0 = pass ? oB0 : oA0;
    const f32x16& p1 = pass ? oB1 : oA1;
#pragma unroll
    for (int r = 0; r < 16; ++r) {
      const int dr = (r & 3) + 8*(r >> 2) + 4*h;
      Osh[wv][q5][dr]      = p0[r];
      Osh[wv][q5][32 + dr] = p1[r];
    }
    if (h == 0) {
      msh[wv][q5] = pass ? mB : mA;
      lsh[wv][q5] = pass ? lB : lA;
    }
    __syncthreads();
    {
      float mm = fmaxf(fmaxf(msh[0][q], msh[1][q]), fmaxf(msh[2][q], msh[3][q]));
      float e0 = __expf(msh[0][q] - mm), e1 = __expf(msh[1][q] - mm),
            e2 = __expf(msh[2][q] - mm), e3 = __expf(msh[3][q] - mm);
      float L = e0*lsh[0][q] + e1*lsh[1][q] + e2*lsh[2][q] + e3*lsh[3][q];
      float rinv = 1.0f / L;
      bf16x8 outv;
#pragma unroll
      for (int j = 0; j < 8; ++j) {
        float sum = e0*Osh[0][q][d0+j] + e1*Osh[1][q][d0+j]
                  + e2*Osh[2][q][d0+j] + e3*Osh[3][q][d0+j];
        outv[j] = (bf16)(sum * rinv);
      }
      *(bf16x8*)&outb[(size_t)(q0 + pass*32 + q)*DIM + hh*64 + d0] = outv;
    }
    __syncthreads();   // Osh/msh/lsh reused by next pass
  }
}

// ---------------- small kernels ----------------
__global__ __launch_bounds__(256) void rope_init_kernel(float* __restrict__ ct, float* __restrict__ st) {
  int idx = blockIdx.x * 256 + threadIdx.x;
  if (idx >= SEQ * 32) return;
  int s = idx >> 5, i = idx & 31;
  float inv = powf(10000.0f, -(float)i / 32.0f);
  float f = (float)s * inv;
  ct[idx] = cosf(f);
  st[idx] = sinf(f);
}

__global__ __launch_bounds__(256) void cast_kernel(const float* __restrict__ src,
    bf16* __restrict__ dst, int perLayer, int dstStride, int dstOff, int L)
{
  int i = blockIdx.x * 256 + threadIdx.x;
  int e = i * 4;
  if (e >= perLayer * L) return;
  int l = e / perLayer;
  int o = e - l * perLayer;
  float4 v = *(const float4*)(src + e);
  bf16x4 b;
  b[0] = (bf16)v.x; b[1] = (bf16)v.y; b[2] = (bf16)v.z; b[3] = (bf16)v.w;
  *(bf16x4*)(dst + (size_t)l * dstStride + dstOff + o) = b;
}

// Cast W1/W3 into the interleaved layout: W1 row r -> (r/16)*32 + (r%16),
// W3 row r -> (r/16)*32 + 16 + (r%16)  (within each layer's 5632x1024 block).
__global__ __launch_bounds__(256) void cast_interleave_kernel(const float* __restrict__ src,
    bf16* __restrict__ dst, int isW3)
{
  const int PLh = HID * DIM;
  int i = blockIdx.x * 256 + threadIdx.x;
  int e = i * 4;
  if (e >= PLh * NLAYER) return;
  int l = e / PLh;
  int rem = e - l * PLh;
  int r = rem >> 10, c = rem & 1023;
  int dr = (r >> 4) * 32 + (isW3 ? 16 : 0) + (r & 15);
  float4 v = *(const float4*)(src + e);
  bf16x4 b;
  b[0] = (bf16)v.x; b[1] = (bf16)v.y; b[2] = (bf16)v.z; b[3] = (bf16)v.w;
  *(bf16x4*)(dst + (size_t)l * 2 * PLh + (size_t)dr * 1024 + c) = b;
}

__global__ __launch_bounds__(256) void embed_kernel(const int* __restrict__ tok,
    const float* __restrict__ emb, float* __restrict__ h)
{
  int s = blockIdx.x, t = threadIdx.x;
  int v = tok[s];
  ((float4*)(h + (size_t)s * DIM))[t] = ((const float4*)(emb + (size_t)v * DIM))[t];
}

__global__ __launch_bounds__(256) void rmsnorm_kernel(const float* __restrict__ h,
    const float* __restrict__ w, bf16* __restrict__ outb)
{
  int row = blockIdx.x, tid = threadIdx.x;
  float4 v = ((const float4*)(h + (size_t)row * DIM))[tid];
  float ss = v.x*v.x + v.y*v.y + v.z*v.z + v.w*v.w;
#pragma unroll
  for (int off = 1; off < 64; off <<= 1) ss += __shfl_xor(ss, off);
  __shared__ float red[4];
  if ((tid & 63) == 0) red[tid >> 6] = ss;
  __syncthreads();
  float tot = red[0] + red[1] + red[2] + red[3];
  float inv = rsqrtf(tot * (1.0f / DIM) + 1e-5f);
  float4 wv4 = ((const float4*)w)[tid];
  bf16x4 o;
  o[0] = (bf16)(v.x * inv * wv4.x);
  o[1] = (bf16)(v.y * inv * wv4.y);
  o[2] = (bf16)(v.z * inv * wv4.z);
  o[3] = (bf16)(v.w * inv * wv4.w);
  ((bf16x4*)(outb + (size_t)row * DIM))[tid] = o;
}

__global__ __launch_bounds__(256) void final_rms_kernel(const float* __restrict__ hrow,
    const float* __restrict__ w, float* __restrict__ fl)
{
  int tid = threadIdx.x;
  float4 v = ((const float4*)hrow)[tid];
  float ss = v.x*v.x + v.y*v.y + v.z*v.z + v.w*v.w;
#pragma unroll
  for (int off = 1; off < 64; off <<= 1) ss += __shfl_xor(ss, off);
  __shared__ float red[4];
  if ((tid & 63) == 0) red[tid >> 6] = ss;
  __syncthreads();
  float tot = red[0] + red[1] + red[2] + red[3];
  float inv = rsqrtf(tot * (1.0f / DIM) + 1e-5f);
  float4 wv4 = ((const float4*)w)[tid];
  float4 o;
  o.x = v.x * inv * wv4.x;
  o.y = v.y * inv * wv4.y;
  o.z = v.z * inv * wv4.z;
  o.w = v.w * inv * wv4.w;
  ((float4*)fl)[tid] = o;
}

// RoPE over q,k: each thread handles 8 contiguous bf16 (4 rot pairs) in one head.
__global__ __launch_bounds__(256) void rope_kernel(bf16* __restrict__ qkv,
    const float* __restrict__ ct, const float* __restrict__ st)
{
  int idx = blockIdx.x * 256 + threadIdx.x;
  if (idx >= SEQ * 128) return;
  int s = idx >> 7, rem = idx & 127;
  int h = rem >> 3, c8 = rem & 7;
  int d0 = c8 * 8, i0 = c8 * 4;
  float4 cv = *(const float4*)&ct[s*32 + i0];
  float4 sv = *(const float4*)&st[s*32 + i0];
  float c[4]  = {cv.x, cv.y, cv.z, cv.w};
  float sn[4] = {sv.x, sv.y, sv.z, sv.w};
  size_t base = (size_t)s * 3072 + h * 64 + d0;
#pragma unroll
  for (int part = 0; part < 2; ++part) {
    bf16x8 x = *(bf16x8*)&qkv[base + part * 1024];
    bf16x8 o;
#pragma unroll
    for (int p = 0; p < 4; ++p) {
      float xr = (float)x[2*p], xi = (float)x[2*p+1];
      o[2*p]   = (bf16)(xr * c[p] - xi * sn[p]);
      o[2*p+1] = (bf16)(xr * sn[p] + xi * c[p]);
    }
    *(bf16x8*)&qkv[base + part * 1024] = o;
  }
}

// Coalesced V transpose via 64x64 LDS tile: both global sides are bf16x8
// contiguous. Grid: 32 j-tiles x 16 d-tiles = 512 blocks.
__global__ __launch_bounds__(256) void vtrans_kernel(const bf16* __restrict__ qkv,
    bf16* __restrict__ vt)
{
  __shared__ unsigned short T[64][66];   // pad 2: read-col conflicts ~4-way max
  const int tj = blockIdx.x & 31;        // j tile
  const int td = blockIdx.x >> 5;        // d tile
  const int t = threadIdx.x;
  {
    const int j = t >> 2, d0 = (t & 3) * 16;
    const bf16* src = qkv + (size_t)(tj*64 + j)*3072 + 2048 + td*64 + d0;
    bf16x8 a = *(const bf16x8*)src;
    bf16x8 b = *(const bf16x8*)(src + 8);
    union { bf16 v; unsigned short u; } cv;
#pragma unroll
    for (int i = 0; i < 8; ++i) {
      cv.v = a[i]; T[j][d0 + i] = cv.u;
      cv.v = b[i]; T[j][d0 + 8 + i] = cv.u;
    }
  }
  __syncthreads();
  {
    const int d = t >> 2, j0 = (t & 3) * 16;
    union { bf16x8 v; unsigned short u[8]; } oa, ob;
#pragma unroll
    for (int i = 0; i < 8; ++i) {
      oa.u[i] = T[j0 + i][d];
      ob.u[i] = T[j0 + 8 + i][d];
    }
    bf16* dst = vt + (size_t)(td*64 + d)*2048 + tj*64 + j0;
    *(bf16x8*)dst = oa.v;
    *(bf16x8*)(dst + 8) = ob.v;
  }
}

__global__ __launch_bounds__(64) void logits_kernel(const float* __restrict__ fl,
    const float* __restrict__ ow, float* __restrict__ outp)
{
  int v = blockIdx.x, lane = threadIdx.x;
  const float* row = ow + (size_t)v * DIM;
  float s = 0.f;
#pragma unroll
  for (int t = 0; t < 16; ++t) {
    int d = t * 64 + lane;
    s += fl[d] * row[d];
  }
#pragma unroll
  for (int off = 1; off < 64; off <<= 1) s += __shfl_xor(s, off);
  if (lane == 0) outp[v] = s;
}

// ---------------- host ----------------
extern "C" void kernel_launch(void* const* d_in, const int* in_sizes, int n_in,
                              void* d_out, int out_size, void* d_ws, size_t ws_size,
                              hipStream_t stream)
{
  const int*   tokens = (const int*)  d_in[0];
  const float* temb   = (const float*)d_in[1];
  const float* wq  = (const float*)d_in[2];
  const float* wk  = (const float*)d_in[3];
  const float* wvv = (const float*)d_in[4];
  const float* wo  = (const float*)d_in[5];
  const float* w1  = (const float*)d_in[6];
  const float* w2  = (const float*)d_in[7];
  const float* w3  = (const float*)d_in[8];
  const float* anw = (const float*)d_in[9];
  const float* fnw = (const float*)d_in[10];
  const float* finw= (const float*)d_in[11];
  const float* outw= (const float*)d_in[12];
  float* out = (float*)d_out;

  char* wsp = (char*)d_ws;
  size_t off = 0;
  auto take = [&](size_t bytes) -> void* {
    void* r = wsp + off;
    off += (bytes + 255) & ~(size_t)255;
    return r;
  };
  bf16* wqkv = (bf16*)take((size_t)NLAYER * 3072 * DIM * 2);
  bf16* wob  = (bf16*)take((size_t)NLAYER * DIM * DIM * 2);
  bf16* w13  = (bf16*)take((size_t)NLAYER * 2 * HID * DIM * 2);
  bf16* w2b  = (bf16*)take((size_t)NLAYER * DIM * HID * 2);
  float* h   = (float*)take((size_t)SEQ * DIM * 4);
  bf16* xn   = (bf16*)take((size_t)SEQ * DIM * 2);
  bf16* qkvb = (bf16*)take((size_t)SEQ * 3072 * 2);
  bf16* vtb  = (bf16*)take((size_t)DIM * SEQ * 2);
  bf16* attnb= (bf16*)take((size_t)SEQ * DIM * 2);
  bf16* hbb  = (bf16*)take((size_t)SEQ * HID * 2);
  float* ct  = (float*)take((size_t)SEQ * 32 * 4);
  float* st  = (float*)take((size_t)SEQ * 32 * 4);
  float* fl  = (float*)take((size_t)DIM * 4);

  rope_init_kernel<<<SEQ * 32 / 256, 256, 0, stream>>>(ct, st);

  const int PLd = DIM * DIM;        // 1048576
  const int PLh = HID * DIM;        // 2883584
  cast_kernel<<<PLd * NLAYER / 1024, 256, 0, stream>>>(wq,  wqkv, PLd, 3 * PLd, 0,       NLAYER);
  cast_kernel<<<PLd * NLAYER / 1024, 256, 0, stream>>>(wk,  wqkv, PLd, 3 * PLd, PLd,     NLAYER);
  cast_kernel<<<PLd * NLAYER / 1024, 256, 0, stream>>>(wvv, wqkv, PLd, 3 * PLd, 2 * PLd, NLAYER);
  cast_kernel<<<PLd * NLAYER / 1024, 256, 0, stream>>>(wo,  wob,  PLd, PLd,     0,       NLAYER);
  cast_interleave_kernel<<<PLh * NLAYER / 1024, 256, 0, stream>>>(w1, w13, 0);
  cast_interleave_kernel<<<PLh * NLAYER / 1024, 256, 0, stream>>>(w3, w13, 1);
  cast_kernel<<<PLh * NLAYER / 1024, 256, 0, stream>>>(w2,  w2b,  PLh, PLh,     0,       NLAYER);

  embed_kernel<<<SEQ, 256, 0, stream>>>(tokens, temb, h);

  for (int l = 0; l < NLAYER; ++l) {
    const bf16* lwqkv = wqkv + (size_t)l * 3 * PLd;
    const bf16* lwo   = wob  + (size_t)l * PLd;
    const bf16* lw13  = w13  + (size_t)l * 2 * PLh;
    const bf16* lw2   = w2b  + (size_t)l * PLh;

    rmsnorm_kernel<<<SEQ, 256, 0, stream>>>(h, anw + l * DIM, xn);
    gemm_bt<0,128,128><<<dim3(24, 16), 256, 0, stream>>>(xn, lwqkv, qkvb, nullptr, nullptr, SEQ, 3072, DIM);
    rope_kernel<<<SEQ * 128 / 256, 256, 0, stream>>>(qkvb, ct, st);
    vtrans_kernel<<<512, 256, 0, stream>>>(qkvb, vtb);
    attn_kernel<<<dim3(16, 32), 256, 0, stream>>>(qkvb, vtb, attnb);
    gemm_bt<1,64,64><<<dim3(16, 32), 256, 0, stream>>>(attnb, lwo, nullptr, h, h, SEQ, DIM, DIM);
    rmsnorm_kernel<<<SEQ, 256, 0, stream>>>(h, fnw + l * DIM, xn);
    gemm_bt<2,128,128><<<dim3(44, 16), 256, 0, stream>>>(xn, lw13, hbb, nullptr, nullptr, SEQ, 2 * HID, DIM);
    gemm_bt<1,64,64><<<dim3(16, 32), 256, 0, stream>>>(hbb, lw2, nullptr, h, h, SEQ, DIM, HID);
  }

  final_rms_kernel<<<1, 256, 0, stream>>>(h + (size_t)(SEQ - 1) * DIM, finw, fl);
  logits_kernel<<<256, 64, 0, stream>>>(fl, outw, out);
}